// Round 1
// baseline (1426.927 us; speedup 1.0000x reference)
//
#include <hip/hip_runtime.h>
#include <hip/hip_bf16.h>

// ---------------- problem dims ----------------
#define IN_DIM 128
#define HID    256
#define FC1    1024
#define FC2    512
#define NACT   64

// ---------------- small utility kernels ----------------
__global__ void init_kernel(float* deg, int* needed, int n) {
    int i = blockIdx.x * blockDim.x + threadIdx.x;
    if (i < n) { deg[i] = 1.0f; needed[i] = 0; }
}

__global__ void mark_kernel(const int* __restrict__ agent_idx, int* __restrict__ needed, int n) {
    int i = blockIdx.x * blockDim.x + threadIdx.x;
    if (i < n) needed[agent_idx[i]] = 1;
}

__global__ void deg_kernel(const int* __restrict__ dst, float* __restrict__ deg, int E) {
    int e = blockIdx.x * blockDim.x + threadIdx.x;
    if (e < E) atomicAdd(&deg[dst[e]], 1.0f);
}

__global__ void dinv_kernel(float* deg, int n) {
    int i = blockIdx.x * blockDim.x + threadIdx.x;
    if (i < n) deg[i] = rsqrtf(deg[i]);  // deg >= 1 always (self-loops)
}

// agg[i][:] = h[i][:] * dinv[i]^2   (self-loop contribution, also serves as init)
__global__ void selfinit_kernel(const float* __restrict__ h, const float* __restrict__ dinv,
                                float* __restrict__ agg, int n_nodes) {
    int t = blockIdx.x * blockDim.x + threadIdx.x;
    int node = t >> 6;          // 64 threads per node, 4 floats each
    if (node >= n_nodes) return;
    int c = (t & 63) * 4;
    float di = dinv[node];
    float s = di * di;
    float4 hv = *(const float4*)&h[(size_t)node * HID + c];
    float4 o;
    o.x = hv.x * s; o.y = hv.y * s; o.z = hv.z * s; o.w = hv.w * s;
    *(float4*)&agg[(size_t)node * HID + c] = o;
}

// one wave per edge: agg[dst] += h[src] * dinv[src]*dinv[dst]  (skips un-needed dst)
__global__ void scatter_kernel(const int* __restrict__ src, const int* __restrict__ dst,
                               const int* __restrict__ needed, const float* __restrict__ dinv,
                               const float* __restrict__ h, float* __restrict__ agg, int E) {
    int g = blockIdx.x * blockDim.x + threadIdx.x;
    int e = g >> 6;
    if (e >= E) return;
    int d = dst[e];
    if (!needed[d]) return;
    int s = src[e];
    float nrm = dinv[s] * dinv[d];
    int c = (g & 63) * 4;
    float4 hv = *(const float4*)&h[(size_t)s * HID + c];
    float* ap = &agg[(size_t)d * HID + c];
    atomicAdd(ap + 0, hv.x * nrm);
    atomicAdd(ap + 1, hv.y * nrm);
    atomicAdd(ap + 2, hv.z * nrm);
    atomicAdd(ap + 3, hv.w * nrm);
}

// ---------------- tiled f32 GEMM ----------------
// C[M,N] = A[M,K] @ B[K,N] (+ bias[N]).  GATHER: A-row i = relu(Asrc[gidx[i]][:] + gbias[:])
#define BM 64
#define BN 64
#define BK 32
#define TM 4
#define TN 4

template<bool GATHER, bool ADD_BIAS>
__global__ __launch_bounds__(256)
void gemm_f32_kernel(const float* __restrict__ A, const float* __restrict__ B,
                     float* __restrict__ C, const float* __restrict__ bias,
                     const int* __restrict__ gidx, const float* __restrict__ gbias,
                     int M, int N, int K) {
    __shared__ float As[BM][BK + 1];
    __shared__ float Bs[BK][BN];
    int tid = threadIdx.x;
    int bm = blockIdx.x * BM;
    int bn = blockIdx.y * BN;
    int tx = tid & 15;
    int ty = tid >> 4;
    float acc[TM][TN] = {};

    for (int k0 = 0; k0 < K; k0 += BK) {
        #pragma unroll
        for (int t = 0; t < (BM * BK) / 256; ++t) {
            int l = tid + t * 256;
            int r = l >> 5;
            int c = l & 31;
            int gr = bm + r;
            float v = 0.f;
            if (gr < M) {
                if (GATHER) {
                    int sr = gidx[gr];
                    v = A[(size_t)sr * K + (k0 + c)] + gbias[k0 + c];
                    v = fmaxf(v, 0.f);
                } else {
                    v = A[(size_t)gr * K + (k0 + c)];
                }
            }
            As[r][c] = v;
        }
        #pragma unroll
        for (int t = 0; t < (BK * BN) / 256; ++t) {
            int l = tid + t * 256;
            int r = l >> 6;
            int c = l & 63;
            Bs[r][c] = B[(size_t)(k0 + r) * N + (bn + c)];
        }
        __syncthreads();
        #pragma unroll
        for (int kk = 0; kk < BK; ++kk) {
            float af[TM], bf[TN];
            #pragma unroll
            for (int i = 0; i < TM; ++i) af[i] = As[ty * TM + i][kk];
            #pragma unroll
            for (int j = 0; j < TN; ++j) bf[j] = Bs[kk][tx * TN + j];
            #pragma unroll
            for (int i = 0; i < TM; ++i)
                #pragma unroll
                for (int j = 0; j < TN; ++j)
                    acc[i][j] = fmaf(af[i], bf[j], acc[i][j]);
        }
        __syncthreads();
    }
    #pragma unroll
    for (int i = 0; i < TM; ++i) {
        int gr = bm + ty * TM + i;
        if (gr >= M) continue;
        #pragma unroll
        for (int j = 0; j < TN; ++j) {
            int gc = bn + tx * TN + j;
            float v = acc[i][j];
            if (ADD_BIAS) v += bias[gc];
            C[(size_t)gr * N + gc] = v;
        }
    }
}

// ---------------- LayerNorm (+relu) over 1024 cols, in place ----------------
__global__ __launch_bounds__(256)
void ln_relu_kernel(float* __restrict__ s, const float* __restrict__ g, const float* __restrict__ b) {
    int row = blockIdx.x;
    float* p = s + (size_t)row * FC1;
    int tid = threadIdx.x;
    float4 v = *(float4*)&p[tid * 4];
    float sum = v.x + v.y + v.z + v.w;
    float sq = v.x * v.x + v.y * v.y + v.z * v.z + v.w * v.w;
    #pragma unroll
    for (int off = 32; off > 0; off >>= 1) {
        sum += __shfl_down(sum, off);
        sq  += __shfl_down(sq, off);
    }
    __shared__ float ssum[4], ssq[4];
    int wid = tid >> 6;
    if ((tid & 63) == 0) { ssum[wid] = sum; ssq[wid] = sq; }
    __syncthreads();
    float tot = ssum[0] + ssum[1] + ssum[2] + ssum[3];
    float tq  = ssq[0] + ssq[1] + ssq[2] + ssq[3];
    float mu = tot * (1.0f / FC1);
    float var = tq * (1.0f / FC1) - mu * mu;
    float rs = rsqrtf(var + 1e-5f);
    float4 gg = *(const float4*)&g[tid * 4];
    float4 bb = *(const float4*)&b[tid * 4];
    v.x = fmaxf((v.x - mu) * rs * gg.x + bb.x, 0.f);
    v.y = fmaxf((v.y - mu) * rs * gg.y + bb.y, 0.f);
    v.z = fmaxf((v.z - mu) * rs * gg.z + bb.z, 0.f);
    v.w = fmaxf((v.w - mu) * rs * gg.w + bb.w, 0.f);
    *(float4*)&p[tid * 4] = v;
}

// ---------------- final: LN(s2) + a, relu, dot Wq ----------------
__global__ __launch_bounds__(256)
void final_kernel(const float* __restrict__ s2, const float* __restrict__ abuf,
                  const float* __restrict__ g2, const float* __restrict__ b2,
                  const float* __restrict__ Wq, const float* __restrict__ bq,
                  float* __restrict__ out) {
    int row = blockIdx.x;
    const float* p = s2 + (size_t)row * FC2;
    int tid = threadIdx.x;
    float2 v = *(const float2*)&p[tid * 2];
    float sum = v.x + v.y;
    float sq = v.x * v.x + v.y * v.y;
    #pragma unroll
    for (int off = 32; off > 0; off >>= 1) {
        sum += __shfl_down(sum, off);
        sq  += __shfl_down(sq, off);
    }
    __shared__ float ssum[4], ssq[4], spart[4];
    int wid = tid >> 6;
    if ((tid & 63) == 0) { ssum[wid] = sum; ssq[wid] = sq; }
    __syncthreads();
    float tot = ssum[0] + ssum[1] + ssum[2] + ssum[3];
    float tq  = ssq[0] + ssq[1] + ssq[2] + ssq[3];
    float mu = tot * (1.0f / FC2);
    float var = tq * (1.0f / FC2) - mu * mu;
    float rs = rsqrtf(var + 1e-5f);
    float2 a = *(const float2*)&abuf[(size_t)row * FC2 + tid * 2];
    float2 gg = *(const float2*)&g2[tid * 2];
    float2 bb = *(const float2*)&b2[tid * 2];
    float sa0 = fmaxf((v.x - mu) * rs * gg.x + bb.x + a.x, 0.f);
    float sa1 = fmaxf((v.y - mu) * rs * gg.y + bb.y + a.y, 0.f);
    float part = sa0 * Wq[tid * 2] + sa1 * Wq[tid * 2 + 1];
    #pragma unroll
    for (int off = 32; off > 0; off >>= 1) part += __shfl_down(part, off);
    if ((tid & 63) == 0) spart[wid] = part;
    __syncthreads();
    if (tid == 0) out[row] = spart[0] + spart[1] + spart[2] + spart[3] + bq[0];
}

// ---------------- launch ----------------
extern "C" void kernel_launch(void* const* d_in, const int* in_sizes, int n_in,
                              void* d_out, int out_size, void* d_ws, size_t ws_size,
                              hipStream_t stream) {
    const float* x        = (const float*)d_in[0];
    const float* action   = (const float*)d_in[1];
    const int*   edge     = (const int*)d_in[2];
    const int*   agent_idx= (const int*)d_in[3];
    const float* W_gcn    = (const float*)d_in[4];
    const float* b_gcn    = (const float*)d_in[5];
    const float* W1       = (const float*)d_in[6];
    const float* b1       = (const float*)d_in[7];
    const float* g1       = (const float*)d_in[8];
    const float* beta1    = (const float*)d_in[9];
    const float* W2       = (const float*)d_in[10];
    const float* b2       = (const float*)d_in[11];
    const float* g2       = (const float*)d_in[12];
    const float* beta2    = (const float*)d_in[13];
    const float* Wa       = (const float*)d_in[14];
    const float* ba       = (const float*)d_in[15];
    const float* Wq       = (const float*)d_in[16];
    const float* bq       = (const float*)d_in[17];
    float* out = (float*)d_out;

    const int N = in_sizes[0] / IN_DIM;   // 50000
    const int E = in_sizes[2] / 2;        // 800000
    const int A = in_sizes[3];            // 16384
    const int* esrc = edge;
    const int* edst = edge + E;

    // workspace carve-up (256B-aligned)
    char* ws = (char*)d_ws;
    size_t off = 0;
    auto carve = [&](size_t bytes) -> char* {
        char* p = ws + off;
        off += (bytes + 255) & ~(size_t)255;
        return p;
    };
    float* dinv  = (float*)carve((size_t)N * 4);
    int*   needed= (int*)  carve((size_t)N * 4);
    float* h     = (float*)carve((size_t)N * HID * 4);
    float* agg   = (float*)carve((size_t)N * HID * 4);
    float* s1    = (float*)carve((size_t)A * FC1 * 4);
    float* s2    = (float*)carve((size_t)A * FC2 * 4);
    float* abuf  = (float*)carve((size_t)A * FC2 * 4);
    (void)ws_size;

    // 1-4: degree / dinv / needed flags
    init_kernel<<<(N + 255) / 256, 256, 0, stream>>>(dinv, needed, N);
    mark_kernel<<<(A + 255) / 256, 256, 0, stream>>>(agent_idx, needed, A);
    deg_kernel<<<(E + 255) / 256, 256, 0, stream>>>(edst, dinv, E);
    dinv_kernel<<<(N + 255) / 256, 256, 0, stream>>>(dinv, N);

    // 5: h = x @ W_gcn
    {
        dim3 grid((N + BM - 1) / BM, HID / BN);
        gemm_f32_kernel<false, false><<<grid, 256, 0, stream>>>(
            x, W_gcn, h, nullptr, nullptr, nullptr, N, HID, IN_DIM);
    }
    // 6: agg init = self-loop term
    selfinit_kernel<<<(N * 64 + 255) / 256, 256, 0, stream>>>(h, dinv, agg, N);
    // 7: edge scatter (needed dst only)
    scatter_kernel<<<(E * 64 + 255) / 256, 256, 0, stream>>>(esrc, edst, needed, dinv, h, agg, E);

    // 8: s1raw = relu(agg[agent_idx] + b_gcn) @ W1 + b1
    {
        dim3 grid(A / BM, FC1 / BN);
        gemm_f32_kernel<true, true><<<grid, 256, 0, stream>>>(
            agg, W1, s1, b1, agent_idx, b_gcn, A, FC1, HID);
    }
    // 9: s1 = relu(LN(s1raw))
    ln_relu_kernel<<<A, 256, 0, stream>>>(s1, g1, beta1);
    // 10: s2raw = s1 @ W2 + b2
    {
        dim3 grid(A / BM, FC2 / BN);
        gemm_f32_kernel<false, true><<<grid, 256, 0, stream>>>(
            s1, W2, s2, b2, nullptr, nullptr, A, FC2, FC1);
    }
    // 11: abuf = action @ Wa + ba
    {
        dim3 grid(A / BM, FC2 / BN);
        gemm_f32_kernel<false, true><<<grid, 256, 0, stream>>>(
            action, Wa, abuf, ba, nullptr, nullptr, A, FC2, NACT);
    }
    // 12: out = relu(LN(s2) + abuf) @ Wq + bq
    final_kernel<<<A, 256, 0, stream>>>(s2, abuf, g2, beta2, Wq, bq, out);
}

// Round 2
// 699.444 us; speedup vs baseline: 2.0401x; 2.0401x over previous
//
#include <hip/hip_runtime.h>
#include <hip/hip_bf16.h>

// ---------------- problem dims ----------------
#define IN_DIM 128
#define HID    256
#define FC1    1024
#define FC2    512
#define NACT   64

// ---------------- CSR-build + aggregation kernels ----------------
__global__ void init_kernel(int* degcnt, int* needed, int* n_needed, int n) {
    int i = blockIdx.x * blockDim.x + threadIdx.x;
    if (i < n) { degcnt[i] = 0; needed[i] = 0; }
    if (i == 0) *n_needed = 0;
}

// dedup agent_idx -> needed flag + compact unique list
__global__ void mark_kernel(const int* __restrict__ agent_idx, int* __restrict__ needed,
                            int* __restrict__ needed_list, int* __restrict__ n_needed, int A) {
    int i = blockIdx.x * blockDim.x + threadIdx.x;
    if (i < A) {
        int idx = agent_idx[i];
        if (atomicExch(&needed[idx], 1) == 0) {
            int p = atomicAdd(n_needed, 1);
            needed_list[p] = idx;
        }
    }
}

// in-degree over all edges (int atomics, L2-friendly 200KB array)
__global__ void deg_kernel(const int* __restrict__ dst, int* __restrict__ degcnt, int E) {
    int e = blockIdx.x * blockDim.x + threadIdx.x;
    if (e < E) atomicAdd(&degcnt[dst[e]], 1);
}

__global__ void dinv_kernel(const int* __restrict__ degcnt, float* __restrict__ dinv, int n) {
    int i = blockIdx.x * blockDim.x + threadIdx.x;
    if (i < n) dinv[i] = rsqrtf((float)degcnt[i] + 1.0f);  // +1 self-loop
}

// exclusive scan of (needed ? degcnt : 0), 2-level, 256/block
__global__ void scan1_kernel(const int* __restrict__ degcnt, const int* __restrict__ needed,
                             int* __restrict__ offs, int* __restrict__ partials, int n) {
    __shared__ int sh[256];
    int tid = threadIdx.x;
    int i = blockIdx.x * 256 + tid;
    int v = (i < n && needed[i]) ? degcnt[i] : 0;
    sh[tid] = v;
    __syncthreads();
    #pragma unroll
    for (int d = 1; d < 256; d <<= 1) {
        int t = (tid >= d) ? sh[tid - d] : 0;
        __syncthreads();
        sh[tid] += t;
        __syncthreads();
    }
    if (i < n) offs[i] = sh[tid] - v;  // exclusive
    if (tid == 255) partials[blockIdx.x] = sh[255];
}

__global__ void scan2_kernel(int* __restrict__ partials, int nblk) {
    __shared__ int sh[256];
    int tid = threadIdx.x;
    int v = (tid < nblk) ? partials[tid] : 0;
    sh[tid] = v;
    __syncthreads();
    #pragma unroll
    for (int d = 1; d < 256; d <<= 1) {
        int t = (tid >= d) ? sh[tid - d] : 0;
        __syncthreads();
        sh[tid] += t;
        __syncthreads();
    }
    if (tid < nblk) partials[tid] = sh[tid] - v;  // exclusive
}

__global__ void addback_kernel(int* __restrict__ offs, const int* __restrict__ partials,
                               int* __restrict__ cursor, int n) {
    int i = blockIdx.x * 256 + threadIdx.x;
    if (i < n) {
        int o = offs[i] + partials[blockIdx.x];
        offs[i] = o;
        cursor[i] = o;
    }
}

// bucket needed edges' src by dst
__global__ void fill_kernel(const int* __restrict__ src, const int* __restrict__ dst,
                            const int* __restrict__ needed, int* __restrict__ cursor,
                            int* __restrict__ srcbuf, int E) {
    int e = blockIdx.x * blockDim.x + threadIdx.x;
    if (e < E) {
        int d = dst[e];
        if (needed[d]) {
            int pos = atomicAdd(&cursor[d], 1);
            srcbuf[pos] = src[e];
        }
    }
}

// agg[i][:] = h[i][:] * dinv[i]^2   (self-loop contribution, also serves as init)
__global__ void selfinit_kernel(const float* __restrict__ h, const float* __restrict__ dinv,
                                float* __restrict__ agg, int n_nodes) {
    int t = blockIdx.x * blockDim.x + threadIdx.x;
    int node = t >> 6;
    if (node >= n_nodes) return;
    int c = (t & 63) * 4;
    float di = dinv[node];
    float s = di * di;
    float4 hv = *(const float4*)&h[(size_t)node * HID + c];
    float4 o;
    o.x = hv.x * s; o.y = hv.y * s; o.z = hv.z * s; o.w = hv.w * s;
    *(float4*)&agg[(size_t)node * HID + c] = o;
}

// one wave per needed node: registers accumulate 256-wide row over its in-edges
__global__ __launch_bounds__(256)
void gather_kernel(const int* __restrict__ needed_list, const int* __restrict__ n_needed,
                   const int* __restrict__ offs, const int* __restrict__ degcnt,
                   const int* __restrict__ srcbuf, const float* __restrict__ dinv,
                   const float* __restrict__ h, float* __restrict__ agg) {
    int w = (blockIdx.x * 256 + threadIdx.x) >> 6;
    int lane = threadIdx.x & 63;
    if (w >= *n_needed) return;
    int d = needed_list[w];
    int beg = offs[d];
    int cnt = degcnt[d];
    float dd = dinv[d];
    float4 acc = {0.f, 0.f, 0.f, 0.f};
    for (int j = 0; j < cnt; ++j) {
        int s = srcbuf[beg + j];
        float nrm = dinv[s] * dd;
        float4 hv = *(const float4*)&h[(size_t)s * HID + lane * 4];
        acc.x = fmaf(hv.x, nrm, acc.x);
        acc.y = fmaf(hv.y, nrm, acc.y);
        acc.z = fmaf(hv.z, nrm, acc.z);
        acc.w = fmaf(hv.w, nrm, acc.w);
    }
    float* ap = &agg[(size_t)d * HID + lane * 4];
    float4 cur = *(float4*)ap;
    cur.x += acc.x; cur.y += acc.y; cur.z += acc.z; cur.w += acc.w;
    *(float4*)ap = cur;
}

// ---------------- tiled f32 GEMM ----------------
#define BM 64
#define BN 64
#define BK 32
#define TM 4
#define TN 4

template<bool GATHER, bool ADD_BIAS>
__global__ __launch_bounds__(256)
void gemm_f32_kernel(const float* __restrict__ A, const float* __restrict__ B,
                     float* __restrict__ C, const float* __restrict__ bias,
                     const int* __restrict__ gidx, const float* __restrict__ gbias,
                     int M, int N, int K) {
    __shared__ float As[BM][BK + 1];
    __shared__ float Bs[BK][BN];
    int tid = threadIdx.x;
    int bm = blockIdx.x * BM;
    int bn = blockIdx.y * BN;
    int tx = tid & 15;
    int ty = tid >> 4;
    float acc[TM][TN] = {};

    for (int k0 = 0; k0 < K; k0 += BK) {
        #pragma unroll
        for (int t = 0; t < (BM * BK) / 256; ++t) {
            int l = tid + t * 256;
            int r = l >> 5;
            int c = l & 31;
            int gr = bm + r;
            float v = 0.f;
            if (gr < M) {
                if (GATHER) {
                    int sr = gidx[gr];
                    v = A[(size_t)sr * K + (k0 + c)] + gbias[k0 + c];
                    v = fmaxf(v, 0.f);
                } else {
                    v = A[(size_t)gr * K + (k0 + c)];
                }
            }
            As[r][c] = v;
        }
        #pragma unroll
        for (int t = 0; t < (BK * BN) / 256; ++t) {
            int l = tid + t * 256;
            int r = l >> 6;
            int c = l & 63;
            Bs[r][c] = B[(size_t)(k0 + r) * N + (bn + c)];
        }
        __syncthreads();
        #pragma unroll
        for (int kk = 0; kk < BK; ++kk) {
            float af[TM], bf[TN];
            #pragma unroll
            for (int i = 0; i < TM; ++i) af[i] = As[ty * TM + i][kk];
            #pragma unroll
            for (int j = 0; j < TN; ++j) bf[j] = Bs[kk][tx * TN + j];
            #pragma unroll
            for (int i = 0; i < TM; ++i)
                #pragma unroll
                for (int j = 0; j < TN; ++j)
                    acc[i][j] = fmaf(af[i], bf[j], acc[i][j]);
        }
        __syncthreads();
    }
    #pragma unroll
    for (int i = 0; i < TM; ++i) {
        int gr = bm + ty * TM + i;
        if (gr >= M) continue;
        #pragma unroll
        for (int j = 0; j < TN; ++j) {
            int gc = bn + tx * TN + j;
            float v = acc[i][j];
            if (ADD_BIAS) v += bias[gc];
            C[(size_t)gr * N + gc] = v;
        }
    }
}

// ---------------- LayerNorm (+relu) over 1024 cols, in place ----------------
__global__ __launch_bounds__(256)
void ln_relu_kernel(float* __restrict__ s, const float* __restrict__ g, const float* __restrict__ b) {
    int row = blockIdx.x;
    float* p = s + (size_t)row * FC1;
    int tid = threadIdx.x;
    float4 v = *(float4*)&p[tid * 4];
    float sum = v.x + v.y + v.z + v.w;
    float sq = v.x * v.x + v.y * v.y + v.z * v.z + v.w * v.w;
    #pragma unroll
    for (int off = 32; off > 0; off >>= 1) {
        sum += __shfl_down(sum, off);
        sq  += __shfl_down(sq, off);
    }
    __shared__ float ssum[4], ssq[4];
    int wid = tid >> 6;
    if ((tid & 63) == 0) { ssum[wid] = sum; ssq[wid] = sq; }
    __syncthreads();
    float tot = ssum[0] + ssum[1] + ssum[2] + ssum[3];
    float tq  = ssq[0] + ssq[1] + ssq[2] + ssq[3];
    float mu = tot * (1.0f / FC1);
    float var = tq * (1.0f / FC1) - mu * mu;
    float rs = rsqrtf(var + 1e-5f);
    float4 gg = *(const float4*)&g[tid * 4];
    float4 bb = *(const float4*)&b[tid * 4];
    v.x = fmaxf((v.x - mu) * rs * gg.x + bb.x, 0.f);
    v.y = fmaxf((v.y - mu) * rs * gg.y + bb.y, 0.f);
    v.z = fmaxf((v.z - mu) * rs * gg.z + bb.z, 0.f);
    v.w = fmaxf((v.w - mu) * rs * gg.w + bb.w, 0.f);
    *(float4*)&p[tid * 4] = v;
}

// ---------------- final: LN(s2) + a, relu, dot Wq ----------------
__global__ __launch_bounds__(256)
void final_kernel(const float* __restrict__ s2, const float* __restrict__ abuf,
                  const float* __restrict__ g2, const float* __restrict__ b2,
                  const float* __restrict__ Wq, const float* __restrict__ bq,
                  float* __restrict__ out) {
    int row = blockIdx.x;
    const float* p = s2 + (size_t)row * FC2;
    int tid = threadIdx.x;
    float2 v = *(const float2*)&p[tid * 2];
    float sum = v.x + v.y;
    float sq = v.x * v.x + v.y * v.y;
    #pragma unroll
    for (int off = 32; off > 0; off >>= 1) {
        sum += __shfl_down(sum, off);
        sq  += __shfl_down(sq, off);
    }
    __shared__ float ssum[4], ssq[4], spart[4];
    int wid = tid >> 6;
    if ((tid & 63) == 0) { ssum[wid] = sum; ssq[wid] = sq; }
    __syncthreads();
    float tot = ssum[0] + ssum[1] + ssum[2] + ssum[3];
    float tq  = ssq[0] + ssq[1] + ssq[2] + ssq[3];
    float mu = tot * (1.0f / FC2);
    float var = tq * (1.0f / FC2) - mu * mu;
    float rs = rsqrtf(var + 1e-5f);
    float2 a = *(const float2*)&abuf[(size_t)row * FC2 + tid * 2];
    float2 gg = *(const float2*)&g2[tid * 2];
    float2 bb = *(const float2*)&b2[tid * 2];
    float sa0 = fmaxf((v.x - mu) * rs * gg.x + bb.x + a.x, 0.f);
    float sa1 = fmaxf((v.y - mu) * rs * gg.y + bb.y + a.y, 0.f);
    float part = sa0 * Wq[tid * 2] + sa1 * Wq[tid * 2 + 1];
    #pragma unroll
    for (int off = 32; off > 0; off >>= 1) part += __shfl_down(part, off);
    if ((tid & 63) == 0) spart[wid] = part;
    __syncthreads();
    if (tid == 0) out[row] = spart[0] + spart[1] + spart[2] + spart[3] + bq[0];
}

// ---------------- launch ----------------
extern "C" void kernel_launch(void* const* d_in, const int* in_sizes, int n_in,
                              void* d_out, int out_size, void* d_ws, size_t ws_size,
                              hipStream_t stream) {
    const float* x        = (const float*)d_in[0];
    const float* action   = (const float*)d_in[1];
    const int*   edge     = (const int*)d_in[2];
    const int*   agent_idx= (const int*)d_in[3];
    const float* W_gcn    = (const float*)d_in[4];
    const float* b_gcn    = (const float*)d_in[5];
    const float* W1       = (const float*)d_in[6];
    const float* b1       = (const float*)d_in[7];
    const float* g1       = (const float*)d_in[8];
    const float* beta1    = (const float*)d_in[9];
    const float* W2       = (const float*)d_in[10];
    const float* b2       = (const float*)d_in[11];
    const float* g2       = (const float*)d_in[12];
    const float* beta2    = (const float*)d_in[13];
    const float* Wa       = (const float*)d_in[14];
    const float* ba       = (const float*)d_in[15];
    const float* Wq       = (const float*)d_in[16];
    const float* bq       = (const float*)d_in[17];
    float* out = (float*)d_out;

    const int N = in_sizes[0] / IN_DIM;   // 50000
    const int E = in_sizes[2] / 2;        // 800000
    const int A = in_sizes[3];            // 16384
    const int* esrc = edge;
    const int* edst = edge + E;

    // workspace carve-up (256B-aligned)
    char* ws = (char*)d_ws;
    size_t off = 0;
    auto carve = [&](size_t bytes) -> char* {
        char* p = ws + off;
        off += (bytes + 255) & ~(size_t)255;
        return p;
    };
    int*   degcnt     = (int*)  carve((size_t)N * 4);
    int*   needed     = (int*)  carve((size_t)N * 4);
    float* dinv       = (float*)carve((size_t)N * 4);
    int*   offs       = (int*)  carve((size_t)N * 4);
    int*   cursor     = (int*)  carve((size_t)N * 4);
    int*   partials   = (int*)  carve(1024 * 4);
    int*   needed_list= (int*)  carve((size_t)A * 4);
    int*   n_needed   = (int*)  carve(256);
    int*   srcbuf     = (int*)  carve((size_t)E * 4);
    float* h          = (float*)carve((size_t)N * HID * 4);
    float* agg        = (float*)carve((size_t)N * HID * 4);
    float* s1         = (float*)carve((size_t)A * FC1 * 4);
    float* s2         = (float*)carve((size_t)A * FC2 * 4);
    float* abuf       = (float*)carve((size_t)A * FC2 * 4);
    (void)ws_size;

    const int nblk_scan = (N + 255) / 256;  // 196

    // CSR build
    init_kernel<<<(N + 255) / 256, 256, 0, stream>>>(degcnt, needed, n_needed, N);
    mark_kernel<<<(A + 255) / 256, 256, 0, stream>>>(agent_idx, needed, needed_list, n_needed, A);
    deg_kernel<<<(E + 255) / 256, 256, 0, stream>>>(edst, degcnt, E);
    dinv_kernel<<<(N + 255) / 256, 256, 0, stream>>>(degcnt, dinv, N);
    scan1_kernel<<<nblk_scan, 256, 0, stream>>>(degcnt, needed, offs, partials, N);
    scan2_kernel<<<1, 256, 0, stream>>>(partials, nblk_scan);
    addback_kernel<<<nblk_scan, 256, 0, stream>>>(offs, partials, cursor, N);
    fill_kernel<<<(E + 255) / 256, 256, 0, stream>>>(esrc, edst, needed, cursor, srcbuf, E);

    // h = x @ W_gcn
    {
        dim3 grid((N + BM - 1) / BM, HID / BN);
        gemm_f32_kernel<false, false><<<grid, 256, 0, stream>>>(
            x, W_gcn, h, nullptr, nullptr, nullptr, N, HID, IN_DIM);
    }
    // agg init = self-loop term, then CSR gather for needed nodes
    selfinit_kernel<<<(N * 64 + 255) / 256, 256, 0, stream>>>(h, dinv, agg, N);
    gather_kernel<<<(A + 3) / 4, 256, 0, stream>>>(needed_list, n_needed, offs, degcnt,
                                                   srcbuf, dinv, h, agg);

    // MLP
    {
        dim3 grid(A / BM, FC1 / BN);
        gemm_f32_kernel<true, true><<<grid, 256, 0, stream>>>(
            agg, W1, s1, b1, agent_idx, b_gcn, A, FC1, HID);
    }
    ln_relu_kernel<<<A, 256, 0, stream>>>(s1, g1, beta1);
    {
        dim3 grid(A / BM, FC2 / BN);
        gemm_f32_kernel<false, true><<<grid, 256, 0, stream>>>(
            s1, W2, s2, b2, nullptr, nullptr, A, FC2, FC1);
    }
    {
        dim3 grid(A / BM, FC2 / BN);
        gemm_f32_kernel<false, true><<<grid, 256, 0, stream>>>(
            action, Wa, abuf, ba, nullptr, nullptr, A, FC2, NACT);
    }
    final_kernel<<<A, 256, 0, stream>>>(s2, abuf, g2, beta2, Wq, bq, out);
}

// Round 3
// 212.747 us; speedup vs baseline: 6.7072x; 3.2877x over previous
//
#include <hip/hip_runtime.h>
#include <hip/hip_bf16.h>

typedef _Float16 f16;
typedef _Float16 __attribute__((ext_vector_type(8))) half8;
typedef _Float16 __attribute__((ext_vector_type(4))) half4;
typedef float __attribute__((ext_vector_type(4))) floatx4;

#define IN_DIM 128
#define HID    256
#define FC1    1024
#define FC2    512
#define NACT   64

// ---------------- CSR build ----------------
__global__ void init_kernel(int* degcnt, int* needed, int* n_needed, int n) {
    int i = blockIdx.x * blockDim.x + threadIdx.x;
    if (i < n) { degcnt[i] = 0; needed[i] = 0; }
    if (i == 0) *n_needed = 0;
}

// dedup agent nodes; needed[node] = slot+1 (0 = not needed)
__global__ void mark_kernel(const int* __restrict__ agent_idx, int* __restrict__ needed,
                            int* __restrict__ needed_list, int* __restrict__ n_needed, int A) {
    int i = blockIdx.x * blockDim.x + threadIdx.x;
    if (i < A) {
        int idx = agent_idx[i];
        if (atomicCAS(&needed[idx], 0, -1) == 0) {
            int p = atomicAdd(n_needed, 1);
            needed_list[p] = idx;
            needed[idx] = p + 1;
        }
    }
}

__global__ void slot_kernel(const int* __restrict__ agent_idx, const int* __restrict__ needed,
                            int* __restrict__ agent_slot, int A) {
    int i = blockIdx.x * blockDim.x + threadIdx.x;
    if (i < A) agent_slot[i] = needed[agent_idx[i]] - 1;
}

__global__ void deg_kernel(const int* __restrict__ dst, int* __restrict__ degcnt, int E) {
    int e = blockIdx.x * blockDim.x + threadIdx.x;
    if (e < E) atomicAdd(&degcnt[dst[e]], 1);
}

__global__ void dinv_kernel(const int* __restrict__ degcnt, float* __restrict__ dinv, int n) {
    int i = blockIdx.x * blockDim.x + threadIdx.x;
    if (i < n) dinv[i] = rsqrtf((float)degcnt[i] + 1.0f);  // +1 self-loop
}

__global__ void scan1_kernel(const int* __restrict__ degcnt, const int* __restrict__ needed,
                             int* __restrict__ offs, int* __restrict__ partials, int n) {
    __shared__ int sh[256];
    int tid = threadIdx.x;
    int i = blockIdx.x * 256 + tid;
    int v = (i < n && needed[i] != 0) ? degcnt[i] : 0;
    sh[tid] = v;
    __syncthreads();
    #pragma unroll
    for (int d = 1; d < 256; d <<= 1) {
        int t = (tid >= d) ? sh[tid - d] : 0;
        __syncthreads();
        sh[tid] += t;
        __syncthreads();
    }
    if (i < n) offs[i] = sh[tid] - v;
    if (tid == 255) partials[blockIdx.x] = sh[255];
}

__global__ void scan2_kernel(int* __restrict__ partials, int nblk) {
    __shared__ int sh[256];
    int tid = threadIdx.x;
    int v = (tid < nblk) ? partials[tid] : 0;
    sh[tid] = v;
    __syncthreads();
    #pragma unroll
    for (int d = 1; d < 256; d <<= 1) {
        int t = (tid >= d) ? sh[tid - d] : 0;
        __syncthreads();
        sh[tid] += t;
        __syncthreads();
    }
    if (tid < nblk) partials[tid] = sh[tid] - v;
}

__global__ void addback_kernel(int* __restrict__ offs, const int* __restrict__ partials,
                               int* __restrict__ cursor, int n) {
    int i = blockIdx.x * 256 + threadIdx.x;
    if (i < n) {
        int o = offs[i] + partials[blockIdx.x];
        offs[i] = o;
        cursor[i] = o;
    }
}

__global__ void fill_kernel(const int* __restrict__ src, const int* __restrict__ dst,
                            const int* __restrict__ needed, int* __restrict__ cursor,
                            int* __restrict__ srcbuf, int E) {
    int e = blockIdx.x * blockDim.x + threadIdx.x;
    if (e < E) {
        int d = dst[e];
        if (needed[d] != 0) {
            int pos = atomicAdd(&cursor[d], 1);
            srcbuf[pos] = src[e];
        }
    }
}

// ---------------- aggregate x (128-d) per unique needed node, write f16 ----------------
__global__ __launch_bounds__(256)
void gather_x_kernel(const int* __restrict__ needed_list, const int* __restrict__ n_needed,
                     const int* __restrict__ offs, const int* __restrict__ degcnt,
                     const int* __restrict__ srcbuf, const float* __restrict__ dinv,
                     const float* __restrict__ x, f16* __restrict__ xagg) {
    int w = (blockIdx.x * 256 + threadIdx.x) >> 6;
    int lane = threadIdx.x & 63;
    if (w >= *n_needed) return;
    int d = needed_list[w];
    float dd = dinv[d];
    int beg = offs[d], cnt = degcnt[d];
    float2 xs = *(const float2*)&x[(size_t)d * IN_DIM + lane * 2];
    float ax = xs.x * dd * dd, ay = xs.y * dd * dd;
    for (int j = 0; j < cnt; ++j) {
        int s = srcbuf[beg + j];
        float nrm = dinv[s] * dd;
        float2 xv = *(const float2*)&x[(size_t)s * IN_DIM + lane * 2];
        ax = fmaf(xv.x, nrm, ax);
        ay = fmaf(xv.y, nrm, ay);
    }
    union { f16 h[2]; unsigned u; } pk;
    pk.h[0] = (f16)ax; pk.h[1] = (f16)ay;
    *(unsigned*)&xagg[(size_t)w * IN_DIM + lane * 2] = pk.u;
}

// ---------------- weight prep: f32 [K,N] -> f16 [N,K] ----------------
__global__ __launch_bounds__(256)
void transpose_cvt_kernel(const float* __restrict__ in, f16* __restrict__ out, int K, int N) {
    __shared__ f16 tile[32][33];
    int k0 = blockIdx.x * 32, n0 = blockIdx.y * 32;
    int tx = threadIdx.x & 31, ty = threadIdx.x >> 5;
    #pragma unroll
    for (int i = 0; i < 4; ++i)
        tile[ty + i * 8][tx] = (f16)in[(size_t)(k0 + ty + i * 8) * N + n0 + tx];
    __syncthreads();
    #pragma unroll
    for (int i = 0; i < 4; ++i)
        out[(size_t)(n0 + ty + i * 8) * K + k0 + tx] = tile[tx][ty + i * 8];
}

__global__ void cvt_f16_kernel(const float* __restrict__ in, f16* __restrict__ out, int n4) {
    int i = blockIdx.x * blockDim.x + threadIdx.x;
    if (i < n4) {
        float4 v = *(const float4*)&in[(size_t)i * 4];
        union { f16 h[4]; unsigned long long u; } pk;
        pk.h[0] = (f16)v.x; pk.h[1] = (f16)v.y; pk.h[2] = (f16)v.z; pk.h[3] = (f16)v.w;
        *(unsigned long long*)&out[(size_t)i * 4] = pk.u;
    }
}

// ---------------- f16 MFMA GEMM: C[M,N] = A[M,K] @ BT[N,K]^T + bias ----------------
// 128x128 tile, BK=32, 4 waves (each 64x64 = 4x4 frags of 16x16x32).
template<bool GATHER, bool RELU, bool LIMIT>
__global__ __launch_bounds__(256)
void gemm_f16_kernel(const f16* __restrict__ A, const f16* __restrict__ BT,
                     f16* __restrict__ C, const float* __restrict__ bias,
                     const int* __restrict__ gidx, const int* __restrict__ limit,
                     int N, int K) {
    if (LIMIT && (int)(blockIdx.x * 128) >= *limit) return;
    __shared__ __align__(16) f16 Asm[128 * 32];
    __shared__ __align__(16) f16 Bsm[128 * 32];
    const int tid = threadIdx.x;
    const int lane = tid & 63;
    const int wave = tid >> 6;
    const int wr = wave >> 1, wc = wave & 1;
    const long bm = (long)blockIdx.x * 128, bn = (long)blockIdx.y * 128;

    // staging source offsets (2 x 16B chunks of A and BT per thread)
    // LDS chunk ci: row r=ci>>2, slot c=ci&3 holds global k-chunk c^(r&3)  (XOR swizzle)
    size_t aoff[2], boff[2];
    #pragma unroll
    for (int t = 0; t < 2; ++t) {
        int ci = t * 256 + tid;
        int r = ci >> 2, c = ci & 3;
        int cs = c ^ (r & 3);
        long arow = bm + r;
        if (GATHER) arow = gidx[arow];
        aoff[t] = (size_t)arow * K + cs * 8;
        boff[t] = (size_t)(bn + r) * K + cs * 8;
    }
    // LDS fragment read offsets (constant across k-steps)
    int aidx[4], bidx[4];
    const int kc = lane >> 4;
    #pragma unroll
    for (int i = 0; i < 4; ++i) {
        int ar = wr * 64 + i * 16 + (lane & 15);
        aidx[i] = ar * 32 + (kc ^ (ar & 3)) * 8;
        int br = wc * 64 + i * 16 + (lane & 15);
        bidx[i] = br * 32 + (kc ^ (br & 3)) * 8;
    }

    floatx4 acc[4][4] = {};
    for (int k0 = 0; k0 < K; k0 += 32) {
        __syncthreads();  // previous tile fully consumed
        #pragma unroll
        for (int t = 0; t < 2; ++t) {
            __builtin_amdgcn_global_load_lds(
                (const __attribute__((address_space(1))) void*)(A + aoff[t] + k0),
                (__attribute__((address_space(3))) void*)(Asm + (t * 256 + tid) * 8), 16, 0, 0);
            __builtin_amdgcn_global_load_lds(
                (const __attribute__((address_space(1))) void*)(BT + boff[t] + k0),
                (__attribute__((address_space(3))) void*)(Bsm + (t * 256 + tid) * 8), 16, 0, 0);
        }
        __syncthreads();  // staging landed (vmcnt drained at barrier)
        half8 af[4], bf[4];
        #pragma unroll
        for (int i = 0; i < 4; ++i) {
            af[i] = *(const half8*)&Asm[aidx[i]];
            bf[i] = *(const half8*)&Bsm[bidx[i]];
        }
        #pragma unroll
        for (int mi = 0; mi < 4; ++mi)
            #pragma unroll
            for (int ni = 0; ni < 4; ++ni)
                acc[mi][ni] = __builtin_amdgcn_mfma_f32_16x16x32_f16(af[mi], bf[ni], acc[mi][ni], 0, 0, 0);
    }
    // epilogue: C/D layout col=lane&15, row=(lane>>4)*4+q
    const int col0 = (int)bn + wc * 64 + (lane & 15);
    const int row0 = (int)bm + wr * 64 + (lane >> 4) * 4;
    #pragma unroll
    for (int ni = 0; ni < 4; ++ni) {
        int col = col0 + ni * 16;
        float bz = bias[col];
        #pragma unroll
        for (int mi = 0; mi < 4; ++mi) {
            #pragma unroll
            for (int q = 0; q < 4; ++q) {
                int row = row0 + mi * 16 + q;
                float v = acc[mi][ni][q] + bz;
                if (RELU) v = fmaxf(v, 0.f);
                C[(size_t)row * N + col] = (f16)v;
            }
        }
    }
}

// ---------------- LayerNorm + relu over 1024 f16 cols, in place ----------------
__global__ __launch_bounds__(256)
void ln_relu_f16_kernel(f16* __restrict__ s, const float* __restrict__ g, const float* __restrict__ b) {
    int row = blockIdx.x;
    f16* p = s + (size_t)row * FC1;
    int tid = threadIdx.x;
    half4 v = *(const half4*)&p[tid * 4];
    float f0 = (float)v[0], f1 = (float)v[1], f2 = (float)v[2], f3 = (float)v[3];
    float sum = f0 + f1 + f2 + f3;
    float sq = f0 * f0 + f1 * f1 + f2 * f2 + f3 * f3;
    #pragma unroll
    for (int off = 32; off > 0; off >>= 1) {
        sum += __shfl_down(sum, off);
        sq  += __shfl_down(sq, off);
    }
    __shared__ float ssum[4], ssq[4];
    int wid = tid >> 6;
    if ((tid & 63) == 0) { ssum[wid] = sum; ssq[wid] = sq; }
    __syncthreads();
    float tot = ssum[0] + ssum[1] + ssum[2] + ssum[3];
    float tq  = ssq[0] + ssq[1] + ssq[2] + ssq[3];
    float mu = tot * (1.0f / FC1);
    float var = tq * (1.0f / FC1) - mu * mu;
    float rs = rsqrtf(var + 1e-5f);
    float4 gg = *(const float4*)&g[tid * 4];
    float4 bb = *(const float4*)&b[tid * 4];
    half4 o;
    o[0] = (f16)fmaxf((f0 - mu) * rs * gg.x + bb.x, 0.f);
    o[1] = (f16)fmaxf((f1 - mu) * rs * gg.y + bb.y, 0.f);
    o[2] = (f16)fmaxf((f2 - mu) * rs * gg.z + bb.z, 0.f);
    o[3] = (f16)fmaxf((f3 - mu) * rs * gg.w + bb.w, 0.f);
    *(half4*)&p[tid * 4] = o;
}

// ---------------- final: relu(LN(s2) + a) @ Wq + bq ----------------
__global__ __launch_bounds__(256)
void final_f16_kernel(const f16* __restrict__ s2, const f16* __restrict__ ab,
                      const float* __restrict__ g2, const float* __restrict__ b2,
                      const float* __restrict__ Wq, const float* __restrict__ bq,
                      float* __restrict__ out) {
    int row = blockIdx.x;
    const f16* p = s2 + (size_t)row * FC2;
    int tid = threadIdx.x;
    float v0 = (float)p[tid * 2], v1 = (float)p[tid * 2 + 1];
    float sum = v0 + v1;
    float sq = v0 * v0 + v1 * v1;
    #pragma unroll
    for (int off = 32; off > 0; off >>= 1) {
        sum += __shfl_down(sum, off);
        sq  += __shfl_down(sq, off);
    }
    __shared__ float ssum[4], ssq[4], spart[4];
    int wid = tid >> 6;
    if ((tid & 63) == 0) { ssum[wid] = sum; ssq[wid] = sq; }
    __syncthreads();
    float tot = ssum[0] + ssum[1] + ssum[2] + ssum[3];
    float tq  = ssq[0] + ssq[1] + ssq[2] + ssq[3];
    float mu = tot * (1.0f / FC2);
    float var = tq * (1.0f / FC2) - mu * mu;
    float rs = rsqrtf(var + 1e-5f);
    float a0 = (float)ab[(size_t)row * FC2 + tid * 2];
    float a1 = (float)ab[(size_t)row * FC2 + tid * 2 + 1];
    float g0 = g2[tid * 2], g1 = g2[tid * 2 + 1];
    float bb0 = b2[tid * 2], bb1 = b2[tid * 2 + 1];
    float sa0 = fmaxf((v0 - mu) * rs * g0 + bb0 + a0, 0.f);
    float sa1 = fmaxf((v1 - mu) * rs * g1 + bb1 + a1, 0.f);
    float part = sa0 * Wq[tid * 2] + sa1 * Wq[tid * 2 + 1];
    #pragma unroll
    for (int off = 32; off > 0; off >>= 1) part += __shfl_down(part, off);
    if ((tid & 63) == 0) spart[wid] = part;
    __syncthreads();
    if (tid == 0) out[row] = spart[0] + spart[1] + spart[2] + spart[3] + bq[0];
}

// ---------------- launch ----------------
extern "C" void kernel_launch(void* const* d_in, const int* in_sizes, int n_in,
                              void* d_out, int out_size, void* d_ws, size_t ws_size,
                              hipStream_t stream) {
    const float* x        = (const float*)d_in[0];
    const float* action   = (const float*)d_in[1];
    const int*   edge     = (const int*)d_in[2];
    const int*   agent_idx= (const int*)d_in[3];
    const float* W_gcn    = (const float*)d_in[4];
    const float* b_gcn    = (const float*)d_in[5];
    const float* W1       = (const float*)d_in[6];
    const float* b1       = (const float*)d_in[7];
    const float* g1       = (const float*)d_in[8];
    const float* beta1    = (const float*)d_in[9];
    const float* W2       = (const float*)d_in[10];
    const float* b2       = (const float*)d_in[11];
    const float* g2       = (const float*)d_in[12];
    const float* beta2    = (const float*)d_in[13];
    const float* Wa       = (const float*)d_in[14];
    const float* ba       = (const float*)d_in[15];
    const float* Wq       = (const float*)d_in[16];
    const float* bq       = (const float*)d_in[17];
    float* out = (float*)d_out;

    const int N = in_sizes[0] / IN_DIM;   // 50000
    const int E = in_sizes[2] / 2;        // 800000
    const int A = in_sizes[3];            // 16384
    const int* esrc = edge;
    const int* edst = edge + E;

    char* ws = (char*)d_ws;
    size_t off = 0;
    auto carve = [&](size_t bytes) -> char* {
        char* p = ws + off;
        off += (bytes + 255) & ~(size_t)255;
        return p;
    };
    int*   degcnt     = (int*)  carve((size_t)N * 4);
    int*   needed     = (int*)  carve((size_t)N * 4);
    float* dinv       = (float*)carve((size_t)N * 4);
    int*   offs       = (int*)  carve((size_t)N * 4);
    int*   cursor     = (int*)  carve((size_t)N * 4);
    int*   partials   = (int*)  carve(1024 * 4);
    int*   needed_list= (int*)  carve((size_t)A * 4);
    int*   n_needed   = (int*)  carve(256);
    int*   agent_slot = (int*)  carve((size_t)A * 4);
    int*   srcbuf     = (int*)  carve((size_t)E * 4);
    f16*   WgcnT      = (f16*)  carve((size_t)HID * IN_DIM * 2);
    f16*   W1T        = (f16*)  carve((size_t)FC1 * HID * 2);
    f16*   W2T        = (f16*)  carve((size_t)FC2 * FC1 * 2);
    f16*   WaT        = (f16*)  carve((size_t)FC2 * NACT * 2);
    f16*   act16      = (f16*)  carve((size_t)A * NACT * 2);
    f16*   xagg       = (f16*)  carve((size_t)A * IN_DIM * 2);
    f16*   z          = (f16*)  carve((size_t)A * HID * 2);
    f16*   s1         = (f16*)  carve((size_t)A * FC1 * 2);
    f16*   s2         = (f16*)  carve((size_t)A * FC2 * 2);
    f16*   abuf       = (f16*)  carve((size_t)A * FC2 * 2);
    (void)ws_size;

    const int nblk_scan = (N + 255) / 256;

    // CSR build
    init_kernel<<<(N + 255) / 256, 256, 0, stream>>>(degcnt, needed, n_needed, N);
    mark_kernel<<<(A + 255) / 256, 256, 0, stream>>>(agent_idx, needed, needed_list, n_needed, A);
    slot_kernel<<<(A + 255) / 256, 256, 0, stream>>>(agent_idx, needed, agent_slot, A);
    deg_kernel<<<(E + 255) / 256, 256, 0, stream>>>(edst, degcnt, E);
    dinv_kernel<<<(N + 255) / 256, 256, 0, stream>>>(degcnt, dinv, N);
    scan1_kernel<<<nblk_scan, 256, 0, stream>>>(degcnt, needed, offs, partials, N);
    scan2_kernel<<<1, 256, 0, stream>>>(partials, nblk_scan);
    addback_kernel<<<nblk_scan, 256, 0, stream>>>(offs, partials, cursor, N);
    fill_kernel<<<(E + 255) / 256, 256, 0, stream>>>(esrc, edst, needed, cursor, srcbuf, E);

    // weight prep (f16, transposed to [N,K])
    transpose_cvt_kernel<<<dim3(IN_DIM / 32, HID / 32), 256, 0, stream>>>(W_gcn, WgcnT, IN_DIM, HID);
    transpose_cvt_kernel<<<dim3(HID / 32, FC1 / 32), 256, 0, stream>>>(W1, W1T, HID, FC1);
    transpose_cvt_kernel<<<dim3(FC1 / 32, FC2 / 32), 256, 0, stream>>>(W2, W2T, FC1, FC2);
    transpose_cvt_kernel<<<dim3(NACT / 32, FC2 / 32), 256, 0, stream>>>(Wa, WaT, NACT, FC2);
    cvt_f16_kernel<<<(A * NACT / 4 + 255) / 256, 256, 0, stream>>>(action, act16, A * NACT / 4);

    // aggregate x per unique node (f32 accumulate, f16 store)
    gather_x_kernel<<<(A + 3) / 4, 256, 0, stream>>>(needed_list, n_needed, offs, degcnt,
                                                     srcbuf, dinv, x, xagg);

    // z = relu(xagg @ W_gcn + b_gcn)    [U,256] f16
    gemm_f16_kernel<false, true, true><<<dim3(A / 128, HID / 128), 256, 0, stream>>>(
        xagg, WgcnT, z, b_gcn, nullptr, n_needed, HID, IN_DIM);
    // s1raw = z[agent_slot] @ W1 + b1   [A,1024] f16
    gemm_f16_kernel<true, false, false><<<dim3(A / 128, FC1 / 128), 256, 0, stream>>>(
        z, W1T, s1, b1, agent_slot, nullptr, FC1, HID);
    // s1 = relu(LN(s1raw))
    ln_relu_f16_kernel<<<A, 256, 0, stream>>>(s1, g1, beta1);
    // s2raw = s1 @ W2 + b2              [A,512] f16
    gemm_f16_kernel<false, false, false><<<dim3(A / 128, FC2 / 128), 256, 0, stream>>>(
        s1, W2T, s2, b2, nullptr, nullptr, FC2, FC1);
    // abuf = action @ Wa + ba           [A,512] f16
    gemm_f16_kernel<false, false, false><<<dim3(A / 128, FC2 / 128), 256, 0, stream>>>(
        act16, WaT, abuf, ba, nullptr, nullptr, FC2, NACT);
    // out = relu(LN(s2) + abuf) @ Wq + bq
    final_f16_kernel<<<A, 256, 0, stream>>>(s2, abuf, g2, beta2, Wq, bq, out);
}

// Round 4
// 187.754 us; speedup vs baseline: 7.6000x; 1.1331x over previous
//
#include <hip/hip_runtime.h>
#include <hip/hip_bf16.h>

typedef _Float16 f16;
typedef _Float16 __attribute__((ext_vector_type(8))) half8;
typedef _Float16 __attribute__((ext_vector_type(4))) half4;
typedef float __attribute__((ext_vector_type(4))) floatx4;

#define IN_DIM 128
#define HID    256
#define FC1    1024
#define FC2    512
#define NACT   64

// ================= fused prep =================
// blocks [0,196): init degcnt/needed/n_needed
// then weight transposes (f32 [K,N] -> f16 [N,K]) and f32->f16 converts
__device__ __forceinline__ void transpose_tile(const float* __restrict__ in, f16* __restrict__ out,
                                               int K, int N, int bx, int by, int tid) {
    __shared__ f16 tile[32][33];
    int k0 = bx * 32, n0 = by * 32;
    int tx = tid & 31, ty = tid >> 5;
    #pragma unroll
    for (int i = 0; i < 4; ++i)
        tile[ty + i * 8][tx] = (f16)in[(size_t)(k0 + ty + i * 8) * N + n0 + tx];
    __syncthreads();
    #pragma unroll
    for (int i = 0; i < 4; ++i)
        out[(size_t)(n0 + ty + i * 8) * K + k0 + tx] = tile[tx][ty + i * 8];
}

__device__ __forceinline__ void cvt8(const float* __restrict__ in, f16* __restrict__ out, long gi) {
    float4 a = *(const float4*)&in[gi * 8];
    float4 b = *(const float4*)&in[gi * 8 + 4];
    half8 pk;
    pk[0] = (f16)a.x; pk[1] = (f16)a.y; pk[2] = (f16)a.z; pk[3] = (f16)a.w;
    pk[4] = (f16)b.x; pk[5] = (f16)b.y; pk[6] = (f16)b.z; pk[7] = (f16)b.w;
    *(half8*)&out[gi * 8] = pk;
}

__global__ __launch_bounds__(256)
void prep_kernel(const float* __restrict__ Wgcn, const float* __restrict__ W1,
                 const float* __restrict__ W2, const float* __restrict__ Wa,
                 const float* __restrict__ action, const float* __restrict__ x,
                 f16* WgcnT, f16* W1T, f16* W2T, f16* WaT, f16* act16, f16* x16,
                 int* degcnt, int* needed, int* n_needed, int N, int A) {
    int b = blockIdx.x, tid = threadIdx.x;
    if (b < 196) {
        int i = b * 256 + tid;
        if (i < N) { degcnt[i] = 0; needed[i] = 0; }
        if (b == 0 && tid == 0) *n_needed = 0;
        return;
    }
    b -= 196;
    if (b < 32)  { transpose_tile(Wgcn, WgcnT, IN_DIM, HID, b & 3, b >> 2, tid); return; }
    b -= 32;
    if (b < 256) { transpose_tile(W1, W1T, HID, FC1, b & 7, b >> 3, tid); return; }
    b -= 256;
    if (b < 512) { transpose_tile(W2, W2T, FC1, FC2, b & 31, b >> 5, tid); return; }
    b -= 512;
    if (b < 32)  { transpose_tile(Wa, WaT, NACT, FC2, b & 1, b >> 1, tid); return; }
    b -= 32;
    if (b < 512) { cvt8(action, act16, (long)b * 256 + tid); return; }
    b -= 512;
    cvt8(x, x16, (long)b * 256 + tid);   // 3125 blocks
}

// ================= CSR build =================
__global__ void markdeg_kernel(const int* __restrict__ agent_idx, const int* __restrict__ edst,
                               int* __restrict__ needed, int* __restrict__ needed_list,
                               int* __restrict__ n_needed, int* __restrict__ degcnt, int A, int E) {
    int b = blockIdx.x;
    if (b < 64) {
        int i = b * 256 + threadIdx.x;
        if (i < A) {
            int idx = agent_idx[i];
            if (atomicCAS(&needed[idx], 0, -1) == 0) {
                int p = atomicAdd(n_needed, 1);
                needed_list[p] = idx;
                needed[idx] = p + 1;
            }
        }
        return;
    }
    int e = (b - 64) * 256 + threadIdx.x;
    if (e < E) atomicAdd(&degcnt[edst[e]], 1);
}

// dinv + agent_slot + scan1 (exclusive scan of needed degrees), fused
__global__ void dss_kernel(const int* __restrict__ degcnt, const int* __restrict__ needed,
                           const int* __restrict__ agent_idx, float* __restrict__ dinv,
                           int* __restrict__ offs, int* __restrict__ partials,
                           int* __restrict__ agent_slot, int N, int A) {
    int b = blockIdx.x;
    if (b < 196) {
        __shared__ int sh[256];
        int tid = threadIdx.x;
        int i = b * 256 + tid;
        int dc = (i < N) ? degcnt[i] : 0;
        if (i < N) dinv[i] = rsqrtf((float)dc + 1.0f);  // +1 self-loop
        int v = (i < N && needed[i] != 0) ? dc : 0;
        sh[tid] = v;
        __syncthreads();
        #pragma unroll
        for (int d = 1; d < 256; d <<= 1) {
            int t = (tid >= d) ? sh[tid - d] : 0;
            __syncthreads();
            sh[tid] += t;
            __syncthreads();
        }
        if (i < N) offs[i] = sh[tid] - v;
        if (tid == 255) partials[b] = sh[255];
        return;
    }
    int i = (b - 196) * 256 + threadIdx.x;
    if (i < A) agent_slot[i] = needed[agent_idx[i]] - 1;
}

__global__ void scan2_kernel(int* __restrict__ partials, int nblk) {
    __shared__ int sh[256];
    int tid = threadIdx.x;
    int v = (tid < nblk) ? partials[tid] : 0;
    sh[tid] = v;
    __syncthreads();
    #pragma unroll
    for (int d = 1; d < 256; d <<= 1) {
        int t = (tid >= d) ? sh[tid - d] : 0;
        __syncthreads();
        sh[tid] += t;
        __syncthreads();
    }
    if (tid < nblk) partials[tid] = sh[tid] - v;
}

__global__ void addback_kernel(int* __restrict__ offs, const int* __restrict__ partials,
                               int* __restrict__ cursor, int n) {
    int i = blockIdx.x * 256 + threadIdx.x;
    if (i < n) {
        int o = offs[i] + partials[blockIdx.x];
        offs[i] = o;
        cursor[i] = o;
    }
}

__global__ void fill_kernel(const int* __restrict__ src, const int* __restrict__ dst,
                            const int* __restrict__ needed, int* __restrict__ cursor,
                            int* __restrict__ srcbuf, int E) {
    int e = blockIdx.x * blockDim.x + threadIdx.x;
    if (e < E) {
        int d = dst[e];
        if (needed[d] != 0) {
            int pos = atomicAdd(&cursor[d], 1);
            srcbuf[pos] = src[e];
        }
    }
}

// ================= aggregate x (f16 in, f32 acc, f16 out) =================
__global__ __launch_bounds__(256)
void gather_x_kernel(const int* __restrict__ needed_list, const int* __restrict__ n_needed,
                     const int* __restrict__ offs, const int* __restrict__ degcnt,
                     const int* __restrict__ srcbuf, const float* __restrict__ dinv,
                     const f16* __restrict__ x16, f16* __restrict__ xagg) {
    int w = (blockIdx.x * 256 + threadIdx.x) >> 6;
    int lane = threadIdx.x & 63;
    if (w >= *n_needed) return;
    int d = needed_list[w];
    float dd = dinv[d];
    int beg = offs[d], cnt = degcnt[d];
    union { unsigned u; f16 h[2]; } ld;
    ld.u = *(const unsigned*)&x16[(size_t)d * IN_DIM + lane * 2];
    float ax = (float)ld.h[0] * dd * dd, ay = (float)ld.h[1] * dd * dd;
    for (int j = 0; j < cnt; ++j) {
        int s = srcbuf[beg + j];
        float nrm = dinv[s] * dd;
        ld.u = *(const unsigned*)&x16[(size_t)s * IN_DIM + lane * 2];
        ax = fmaf((float)ld.h[0], nrm, ax);
        ay = fmaf((float)ld.h[1], nrm, ay);
    }
    union { f16 h[2]; unsigned u; } pk;
    pk.h[0] = (f16)ax; pk.h[1] = (f16)ay;
    *(unsigned*)&xagg[(size_t)w * IN_DIM + lane * 2] = pk.u;
}

// ================= f16 MFMA GEMM, double-buffered issue-early pipeline =================
// C[M,N] = A[M,K] @ BT[N,K]^T + bias; 128x128 tile, BK=32, 4 waves.
template<bool RELU, bool LIMIT>
__global__ __launch_bounds__(256)
void gemm_f16_kernel(const f16* __restrict__ A, const f16* __restrict__ BT,
                     f16* __restrict__ C, const float* __restrict__ bias,
                     const int* __restrict__ limit, int N, int K) {
    if (LIMIT && (int)(blockIdx.x * 128) >= *limit) return;
    __shared__ __align__(16) f16 sm[2][2][128 * 32];
    const int tid = threadIdx.x;
    const int lane = tid & 63;
    const int wave = tid >> 6;
    const int wr = wave >> 1, wc = wave & 1;
    const long bm = (long)blockIdx.x * 128, bn = (long)blockIdx.y * 128;

    // staging: LDS chunk ci -> row r=ci>>2, slot c=ci&3 holds global k-chunk c^(r&3)
    size_t aoff[2], boff[2];
    #pragma unroll
    for (int t = 0; t < 2; ++t) {
        int ci = t * 256 + tid;
        int r = ci >> 2, c = ci & 3;
        int cs = c ^ (r & 3);
        aoff[t] = (size_t)(bm + r) * K + cs * 8;
        boff[t] = (size_t)(bn + r) * K + cs * 8;
    }
    int aidx[4], bidx[4];
    const int kc = lane >> 4;
    #pragma unroll
    for (int i = 0; i < 4; ++i) {
        int ar = wr * 64 + i * 16 + (lane & 15);
        aidx[i] = ar * 32 + (kc ^ (ar & 3)) * 8;
        int br = wc * 64 + i * 16 + (lane & 15);
        bidx[i] = br * 32 + (kc ^ (br & 3)) * 8;
    }

    const int NT = K >> 5;
    auto stage = [&](int buf, int k0) {
        #pragma unroll
        for (int t = 0; t < 2; ++t) {
            __builtin_amdgcn_global_load_lds(
                (const __attribute__((address_space(1))) void*)(A + aoff[t] + k0),
                (__attribute__((address_space(3))) void*)(&sm[buf][0][(t * 256 + tid) * 8]), 16, 0, 0);
            __builtin_amdgcn_global_load_lds(
                (const __attribute__((address_space(1))) void*)(BT + boff[t] + k0),
                (__attribute__((address_space(3))) void*)(&sm[buf][1][(t * 256 + tid) * 8]), 16, 0, 0);
        }
    };

    floatx4 acc[4][4] = {};
    stage(0, 0);
    asm volatile("s_waitcnt vmcnt(0)" ::: "memory");
    __builtin_amdgcn_s_barrier();
    int cur = 0;
    for (int t = 0; t < NT; ++t) {
        if (t + 1 < NT) stage(cur ^ 1, (t + 1) << 5);   // issue next-tile loads early
        half8 af[4], bf[4];
        #pragma unroll
        for (int i = 0; i < 4; ++i) {
            af[i] = *(const half8*)&sm[cur][0][aidx[i]];
            bf[i] = *(const half8*)&sm[cur][1][bidx[i]];
        }
        #pragma unroll
        for (int mi = 0; mi < 4; ++mi)
            #pragma unroll
            for (int ni = 0; ni < 4; ++ni)
                acc[mi][ni] = __builtin_amdgcn_mfma_f32_16x16x32_f16(af[mi], bf[ni], acc[mi][ni], 0, 0, 0);
        asm volatile("s_waitcnt vmcnt(0)" ::: "memory");  // next tile landed
        __builtin_amdgcn_s_barrier();                     // all waves done reading cur
        cur ^= 1;
    }
    // epilogue: C/D layout col=lane&15, row=(lane>>4)*4+q
    const int col0 = (int)bn + wc * 64 + (lane & 15);
    const int row0 = (int)bm + wr * 64 + (lane >> 4) * 4;
    #pragma unroll
    for (int ni = 0; ni < 4; ++ni) {
        int col = col0 + ni * 16;
        float bz = bias[col];
        #pragma unroll
        for (int mi = 0; mi < 4; ++mi) {
            #pragma unroll
            for (int q = 0; q < 4; ++q) {
                int row = row0 + mi * 16 + q;
                float v = acc[mi][ni][q] + bz;
                if (RELU) v = fmaxf(v, 0.f);
                C[(size_t)row * N + col] = (f16)v;
            }
        }
    }
}

// ================= LayerNorm + relu over 1024 f16 cols (unique rows) =================
__global__ __launch_bounds__(256)
void ln_relu_f16_kernel(f16* __restrict__ s, const float* __restrict__ g,
                        const float* __restrict__ b, const int* __restrict__ nn) {
    int row = blockIdx.x;
    if (row >= *nn) return;
    f16* p = s + (size_t)row * FC1;
    int tid = threadIdx.x;
    half4 v = *(const half4*)&p[tid * 4];
    float f0 = (float)v[0], f1 = (float)v[1], f2 = (float)v[2], f3 = (float)v[3];
    float sum = f0 + f1 + f2 + f3;
    float sq = f0 * f0 + f1 * f1 + f2 * f2 + f3 * f3;
    #pragma unroll
    for (int off = 32; off > 0; off >>= 1) {
        sum += __shfl_down(sum, off);
        sq  += __shfl_down(sq, off);
    }
    __shared__ float ssum[4], ssq[4];
    int wid = tid >> 6;
    if ((tid & 63) == 0) { ssum[wid] = sum; ssq[wid] = sq; }
    __syncthreads();
    float tot = ssum[0] + ssum[1] + ssum[2] + ssum[3];
    float tq  = ssq[0] + ssq[1] + ssq[2] + ssq[3];
    float mu = tot * (1.0f / FC1);
    float var = tq * (1.0f / FC1) - mu * mu;
    float rs = rsqrtf(var + 1e-5f);
    float4 gg = *(const float4*)&g[tid * 4];
    float4 bb = *(const float4*)&b[tid * 4];
    half4 o;
    o[0] = (f16)fmaxf((f0 - mu) * rs * gg.x + bb.x, 0.f);
    o[1] = (f16)fmaxf((f1 - mu) * rs * gg.y + bb.y, 0.f);
    o[2] = (f16)fmaxf((f2 - mu) * rs * gg.z + bb.z, 0.f);
    o[3] = (f16)fmaxf((f3 - mu) * rs * gg.w + bb.w, 0.f);
    *(half4*)&p[tid * 4] = o;
}

// ================= final: relu(LN(s2[slot]) + a) @ Wq + bq =================
__global__ __launch_bounds__(256)
void final_f16_kernel(const f16* __restrict__ s2, const f16* __restrict__ ab,
                      const int* __restrict__ agent_slot,
                      const float* __restrict__ g2, const float* __restrict__ b2,
                      const float* __restrict__ Wq, const float* __restrict__ bq,
                      float* __restrict__ out) {
    int row = blockIdx.x;
    int slot = agent_slot[row];
    const f16* p = s2 + (size_t)slot * FC2;
    int tid = threadIdx.x;
    float v0 = (float)p[tid * 2], v1 = (float)p[tid * 2 + 1];
    float sum = v0 + v1;
    float sq = v0 * v0 + v1 * v1;
    #pragma unroll
    for (int off = 32; off > 0; off >>= 1) {
        sum += __shfl_down(sum, off);
        sq  += __shfl_down(sq, off);
    }
    __shared__ float ssum[4], ssq[4], spart[4];
    int wid = tid >> 6;
    if ((tid & 63) == 0) { ssum[wid] = sum; ssq[wid] = sq; }
    __syncthreads();
    float tot = ssum[0] + ssum[1] + ssum[2] + ssum[3];
    float tq  = ssq[0] + ssq[1] + ssq[2] + ssq[3];
    float mu = tot * (1.0f / FC2);
    float var = tq * (1.0f / FC2) - mu * mu;
    float rs = rsqrtf(var + 1e-5f);
    float a0 = (float)ab[(size_t)row * FC2 + tid * 2];
    float a1 = (float)ab[(size_t)row * FC2 + tid * 2 + 1];
    float g0 = g2[tid * 2], g1 = g2[tid * 2 + 1];
    float bb0 = b2[tid * 2], bb1 = b2[tid * 2 + 1];
    float sa0 = fmaxf((v0 - mu) * rs * g0 + bb0 + a0, 0.f);
    float sa1 = fmaxf((v1 - mu) * rs * g1 + bb1 + a1, 0.f);
    float part = sa0 * Wq[tid * 2] + sa1 * Wq[tid * 2 + 1];
    #pragma unroll
    for (int off = 32; off > 0; off >>= 1) part += __shfl_down(part, off);
    if ((tid & 63) == 0) spart[wid] = part;
    __syncthreads();
    if (tid == 0) out[row] = spart[0] + spart[1] + spart[2] + spart[3] + bq[0];
}

// ================= launch =================
extern "C" void kernel_launch(void* const* d_in, const int* in_sizes, int n_in,
                              void* d_out, int out_size, void* d_ws, size_t ws_size,
                              hipStream_t stream) {
    const float* x        = (const float*)d_in[0];
    const float* action   = (const float*)d_in[1];
    const int*   edge     = (const int*)d_in[2];
    const int*   agent_idx= (const int*)d_in[3];
    const float* W_gcn    = (const float*)d_in[4];
    const float* b_gcn    = (const float*)d_in[5];
    const float* W1       = (const float*)d_in[6];
    const float* b1       = (const float*)d_in[7];
    const float* g1       = (const float*)d_in[8];
    const float* beta1    = (const float*)d_in[9];
    const float* W2       = (const float*)d_in[10];
    const float* b2       = (const float*)d_in[11];
    const float* g2       = (const float*)d_in[12];
    const float* beta2    = (const float*)d_in[13];
    const float* Wa       = (const float*)d_in[14];
    const float* ba       = (const float*)d_in[15];
    const float* Wq       = (const float*)d_in[16];
    const float* bq       = (const float*)d_in[17];
    float* out = (float*)d_out;

    const int N = in_sizes[0] / IN_DIM;   // 50000
    const int E = in_sizes[2] / 2;        // 800000
    const int A = in_sizes[3];            // 16384
    const int* esrc = edge;
    const int* edst = edge + E;

    char* ws = (char*)d_ws;
    size_t off = 0;
    auto carve = [&](size_t bytes) -> char* {
        char* p = ws + off;
        off += (bytes + 255) & ~(size_t)255;
        return p;
    };
    int*   degcnt     = (int*)  carve((size_t)N * 4);
    int*   needed     = (int*)  carve((size_t)N * 4);
    float* dinv       = (float*)carve((size_t)N * 4);
    int*   offs       = (int*)  carve((size_t)N * 4);
    int*   cursor     = (int*)  carve((size_t)N * 4);
    int*   partials   = (int*)  carve(1024 * 4);
    int*   needed_list= (int*)  carve((size_t)A * 4);
    int*   n_needed   = (int*)  carve(256);
    int*   agent_slot = (int*)  carve((size_t)A * 4);
    int*   srcbuf     = (int*)  carve((size_t)E * 4);
    f16*   WgcnT      = (f16*)  carve((size_t)HID * IN_DIM * 2);
    f16*   W1T        = (f16*)  carve((size_t)FC1 * HID * 2);
    f16*   W2T        = (f16*)  carve((size_t)FC2 * FC1 * 2);
    f16*   WaT        = (f16*)  carve((size_t)FC2 * NACT * 2);
    f16*   act16      = (f16*)  carve((size_t)A * NACT * 2);
    f16*   x16        = (f16*)  carve((size_t)N * IN_DIM * 2);
    f16*   xagg       = (f16*)  carve((size_t)A * IN_DIM * 2);
    f16*   z          = (f16*)  carve((size_t)A * HID * 2);
    f16*   s1         = (f16*)  carve((size_t)A * FC1 * 2);
    f16*   s2         = (f16*)  carve((size_t)A * FC2 * 2);
    f16*   abuf       = (f16*)  carve((size_t)A * FC2 * 2);
    (void)ws_size;

    const int nblk_scan = (N + 255) / 256;       // 196
    const int eblk = (E + 255) / 256;            // 3125

    // 1: fused prep (init + weight transposes + f16 converts), independent sub-jobs
    prep_kernel<<<196 + 32 + 256 + 512 + 32 + 512 + eblk, 256, 0, stream>>>(
        W_gcn, W1, W2, Wa, action, x, WgcnT, W1T, W2T, WaT, act16, x16,
        degcnt, needed, n_needed, N, A);
    // 2: mark agents + degree count
    markdeg_kernel<<<64 + eblk, 256, 0, stream>>>(agent_idx, edst, needed, needed_list,
                                                  n_needed, degcnt, A, E);
    // 3: dinv + agent_slot + scan level 1
    dss_kernel<<<nblk_scan + 64, 256, 0, stream>>>(degcnt, needed, agent_idx, dinv,
                                                   offs, partials, agent_slot, N, A);
    scan2_kernel<<<1, 256, 0, stream>>>(partials, nblk_scan);
    addback_kernel<<<nblk_scan, 256, 0, stream>>>(offs, partials, cursor, N);
    fill_kernel<<<eblk, 256, 0, stream>>>(esrc, edst, needed, cursor, srcbuf, E);
    // 7: aggregate
    gather_x_kernel<<<(A + 3) / 4, 256, 0, stream>>>(needed_list, n_needed, offs, degcnt,
                                                     srcbuf, dinv, x16, xagg);
    // 8: z = relu(xagg @ Wgcn + b_gcn)   [U,256]
    gemm_f16_kernel<true, true><<<dim3(A / 128, HID / 128), 256, 0, stream>>>(
        xagg, WgcnT, z, b_gcn, n_needed, HID, IN_DIM);
    // 9: s1 = z @ W1 + b1                [U,1024]
    gemm_f16_kernel<false, true><<<dim3(A / 128, FC1 / 128), 256, 0, stream>>>(
        z, W1T, s1, b1, n_needed, FC1, HID);
    // 10: s1 = relu(LN(s1))
    ln_relu_f16_kernel<<<A, 256, 0, stream>>>(s1, g1, beta1, n_needed);
    // 11: s2 = s1 @ W2 + b2              [U,512]
    gemm_f16_kernel<false, true><<<dim3(A / 128, FC2 / 128), 256, 0, stream>>>(
        s1, W2T, s2, b2, n_needed, FC2, FC1);
    // 12: abuf = action @ Wa + ba        [A,512]
    gemm_f16_kernel<false, false><<<dim3(A / 128, FC2 / 128), 256, 0, stream>>>(
        act16, WaT, abuf, ba, nullptr, FC2, NACT);
    // 13: out = relu(LN(s2[slot]) + abuf) @ Wq + bq
    final_f16_kernel<<<A, 256, 0, stream>>>(s2, abuf, agent_slot, g2, beta2, Wq, bq, out);
}

// Round 5
// 181.547 us; speedup vs baseline: 7.8598x; 1.0342x over previous
//
#include <hip/hip_runtime.h>
#include <hip/hip_bf16.h>

typedef _Float16 f16;
typedef _Float16 __attribute__((ext_vector_type(8))) half8;
typedef _Float16 __attribute__((ext_vector_type(4))) half4;
typedef float __attribute__((ext_vector_type(4))) floatx4;

#define IN_DIM 128
#define HID    256
#define FC1    1024
#define FC2    512
#define NACT   64

// ================= fused prep =================
__device__ __forceinline__ void transpose_tile(const float* __restrict__ in, f16* __restrict__ out,
                                               int K, int N, int bx, int by, int tid) {
    __shared__ f16 tile[32][33];
    int k0 = bx * 32, n0 = by * 32;
    int tx = tid & 31, ty = tid >> 5;
    #pragma unroll
    for (int i = 0; i < 4; ++i)
        tile[ty + i * 8][tx] = (f16)in[(size_t)(k0 + ty + i * 8) * N + n0 + tx];
    __syncthreads();
    #pragma unroll
    for (int i = 0; i < 4; ++i)
        out[(size_t)(n0 + ty + i * 8) * K + k0 + tx] = tile[tx][ty + i * 8];
}

__device__ __forceinline__ void cvt8(const float* __restrict__ in, f16* __restrict__ out, long gi) {
    float4 a = *(const float4*)&in[gi * 8];
    float4 b = *(const float4*)&in[gi * 8 + 4];
    half8 pk;
    pk[0] = (f16)a.x; pk[1] = (f16)a.y; pk[2] = (f16)a.z; pk[3] = (f16)a.w;
    pk[4] = (f16)b.x; pk[5] = (f16)b.y; pk[6] = (f16)b.z; pk[7] = (f16)b.w;
    *(half8*)&out[gi * 8] = pk;
}

__global__ __launch_bounds__(256)
void prep_kernel(const float* __restrict__ Wgcn, const float* __restrict__ W1,
                 const float* __restrict__ W2, const float* __restrict__ Wa,
                 const float* __restrict__ action, const float* __restrict__ x,
                 f16* WgcnT, f16* W1T, f16* W2T, f16* WaT, f16* act16, f16* x16,
                 int* degcnt, int* needed, int* n_needed, int N, int A) {
    int b = blockIdx.x, tid = threadIdx.x;
    if (b < 196) {
        int i = b * 256 + tid;
        if (i < N) { degcnt[i] = 0; needed[i] = 0; }
        if (b == 0 && tid == 0) *n_needed = 0;
        return;
    }
    b -= 196;
    if (b < 32)  { transpose_tile(Wgcn, WgcnT, IN_DIM, HID, b & 3, b >> 2, tid); return; }
    b -= 32;
    if (b < 256) { transpose_tile(W1, W1T, HID, FC1, b & 7, b >> 3, tid); return; }
    b -= 256;
    if (b < 512) { transpose_tile(W2, W2T, FC1, FC2, b & 31, b >> 5, tid); return; }
    b -= 512;
    if (b < 32)  { transpose_tile(Wa, WaT, NACT, FC2, b & 1, b >> 1, tid); return; }
    b -= 32;
    if (b < 512) { cvt8(action, act16, (long)b * 256 + tid); return; }
    b -= 512;
    cvt8(x, x16, (long)b * 256 + tid);   // 3125 blocks
}

// ================= CSR build =================
__global__ void markdeg_kernel(const int* __restrict__ agent_idx, const int* __restrict__ edst,
                               int* __restrict__ needed, int* __restrict__ needed_list,
                               int* __restrict__ n_needed, int* __restrict__ degcnt, int A, int E) {
    int b = blockIdx.x;
    if (b < 64) {
        int i = b * 256 + threadIdx.x;
        if (i < A) {
            int idx = agent_idx[i];
            if (atomicCAS(&needed[idx], 0, -1) == 0) {
                int p = atomicAdd(n_needed, 1);
                needed_list[p] = idx;
                needed[idx] = p + 1;
            }
        }
        return;
    }
    int e = (b - 64) * 256 + threadIdx.x;
    if (e < E) atomicAdd(&degcnt[edst[e]], 1);
}

// dinv + agent_slot + scan1, fused
__global__ void dss_kernel(const int* __restrict__ degcnt, const int* __restrict__ needed,
                           const int* __restrict__ agent_idx, float* __restrict__ dinv,
                           int* __restrict__ offs, int* __restrict__ partials,
                           int* __restrict__ agent_slot, int N, int A) {
    int b = blockIdx.x;
    if (b < 196) {
        __shared__ int sh[256];
        int tid = threadIdx.x;
        int i = b * 256 + tid;
        int dc = (i < N) ? degcnt[i] : 0;
        if (i < N) dinv[i] = rsqrtf((float)dc + 1.0f);  // +1 self-loop
        int v = (i < N && needed[i] != 0) ? dc : 0;
        sh[tid] = v;
        __syncthreads();
        #pragma unroll
        for (int d = 1; d < 256; d <<= 1) {
            int t = (tid >= d) ? sh[tid - d] : 0;
            __syncthreads();
            sh[tid] += t;
            __syncthreads();
        }
        if (i < N) offs[i] = sh[tid] - v;
        if (tid == 255) partials[b] = sh[255];
        return;
    }
    int i = (b - 196) * 256 + threadIdx.x;
    if (i < A) agent_slot[i] = needed[agent_idx[i]] - 1;
}

// addback with fused scan of partials (each block scans all 196 partials in LDS)
__global__ void addback_kernel(int* __restrict__ offs, const int* __restrict__ partials,
                               int* __restrict__ cursor, int n, int nblk) {
    __shared__ int sh[256];
    int tid = threadIdx.x;
    int v = (tid < nblk) ? partials[tid] : 0;
    sh[tid] = v;
    __syncthreads();
    #pragma unroll
    for (int d = 1; d < 256; d <<= 1) {
        int t = (tid >= d) ? sh[tid - d] : 0;
        __syncthreads();
        sh[tid] += t;
        __syncthreads();
    }
    int base = (blockIdx.x == 0) ? 0 : sh[blockIdx.x - 1];
    int i = blockIdx.x * 256 + tid;
    if (i < n) {
        int o = offs[i] + base;
        offs[i] = o;
        cursor[i] = o;
    }
}

__global__ void fill_kernel(const int* __restrict__ src, const int* __restrict__ dst,
                            const int* __restrict__ needed, int* __restrict__ cursor,
                            int* __restrict__ srcbuf, int E) {
    int e = blockIdx.x * blockDim.x + threadIdx.x;
    if (e < E) {
        int d = dst[e];
        if (needed[d] != 0) {
            int pos = atomicAdd(&cursor[d], 1);
            srcbuf[pos] = src[e];
        }
    }
}

// ================= aggregate x (f16 in, f32 acc, f16 out) =================
__global__ __launch_bounds__(256)
void gather_x_kernel(const int* __restrict__ needed_list, const int* __restrict__ n_needed,
                     const int* __restrict__ offs, const int* __restrict__ degcnt,
                     const int* __restrict__ srcbuf, const float* __restrict__ dinv,
                     const f16* __restrict__ x16, f16* __restrict__ xagg) {
    int w = (blockIdx.x * 256 + threadIdx.x) >> 6;
    int lane = threadIdx.x & 63;
    if (w >= *n_needed) return;
    int d = needed_list[w];
    float dd = dinv[d];
    int beg = offs[d], cnt = degcnt[d];
    union { unsigned u; f16 h[2]; } ld0, ld1;
    ld0.u = *(const unsigned*)&x16[(size_t)d * IN_DIM + lane * 2];
    float ax = (float)ld0.h[0] * dd * dd, ay = (float)ld0.h[1] * dd * dd;
    int j = 0;
    for (; j + 1 < cnt; j += 2) {   // 2-deep for memory-level parallelism
        int s0 = srcbuf[beg + j], s1 = srcbuf[beg + j + 1];
        float n0 = dinv[s0] * dd, n1 = dinv[s1] * dd;
        ld0.u = *(const unsigned*)&x16[(size_t)s0 * IN_DIM + lane * 2];
        ld1.u = *(const unsigned*)&x16[(size_t)s1 * IN_DIM + lane * 2];
        ax = fmaf((float)ld0.h[0], n0, ax);
        ay = fmaf((float)ld0.h[1], n0, ay);
        ax = fmaf((float)ld1.h[0], n1, ax);
        ay = fmaf((float)ld1.h[1], n1, ay);
    }
    if (j < cnt) {
        int s0 = srcbuf[beg + j];
        float n0 = dinv[s0] * dd;
        ld0.u = *(const unsigned*)&x16[(size_t)s0 * IN_DIM + lane * 2];
        ax = fmaf((float)ld0.h[0], n0, ax);
        ay = fmaf((float)ld0.h[1], n0, ay);
    }
    union { f16 h[2]; unsigned u; } pk;
    pk.h[0] = (f16)ax; pk.h[1] = (f16)ay;
    *(unsigned*)&xagg[(size_t)w * IN_DIM + lane * 2] = pk.u;
}

// ================= f16 MFMA GEMM tile body =================
// 64x128 tile, BK=32, 4 waves (each 32x64 = 2x4 frags of 16x16x32), double-buffered.
template<bool RELU, bool LIMIT>
__device__ __forceinline__ void gemm_tile(f16* __restrict__ smA, f16* __restrict__ smB,
                                          const f16* __restrict__ A, const f16* __restrict__ BT,
                                          f16* __restrict__ C, const float* __restrict__ bias,
                                          const int* __restrict__ limit,
                                          int bx, int by, int N, int K) {
    if (LIMIT && bx * 64 >= *limit) return;
    const int tid = threadIdx.x;
    const int lane = tid & 63;
    const int wave = tid >> 6;
    const int wr = wave >> 1, wc = wave & 1;
    const long bm = (long)bx * 64, bn = (long)by * 128;

    // staging offsets: chunk ci -> row r=ci>>2, slot c=ci&3 holds k-chunk c^(r&3)
    size_t aoff, boff[2];
    {
        int r = tid >> 2, c = tid & 3, cs = c ^ (r & 3);
        aoff = (size_t)(bm + r) * K + cs * 8;
    }
    #pragma unroll
    for (int t = 0; t < 2; ++t) {
        int ci = t * 256 + tid;
        int r = ci >> 2, c = ci & 3, cs = c ^ (r & 3);
        boff[t] = (size_t)(bn + r) * K + cs * 8;
    }
    int aidx[2], bidx[4];
    const int kc = lane >> 4;
    #pragma unroll
    for (int i = 0; i < 2; ++i) {
        int ar = wr * 32 + i * 16 + (lane & 15);
        aidx[i] = ar * 32 + (kc ^ (ar & 3)) * 8;
    }
    #pragma unroll
    for (int i = 0; i < 4; ++i) {
        int br = wc * 64 + i * 16 + (lane & 15);
        bidx[i] = br * 32 + (kc ^ (br & 3)) * 8;
    }

    const int NT = K >> 5;
    auto stage = [&](int buf, int k0) {
        __builtin_amdgcn_global_load_lds(
            (const __attribute__((address_space(1))) void*)(A + aoff + k0),
            (__attribute__((address_space(3))) void*)(&smA[buf * 2048 + tid * 8]), 16, 0, 0);
        #pragma unroll
        for (int t = 0; t < 2; ++t)
            __builtin_amdgcn_global_load_lds(
                (const __attribute__((address_space(1))) void*)(BT + boff[t] + k0),
                (__attribute__((address_space(3))) void*)(&smB[buf * 4096 + (t * 256 + tid) * 8]), 16, 0, 0);
    };

    floatx4 acc[2][4] = {};
    stage(0, 0);
    asm volatile("s_waitcnt vmcnt(0)" ::: "memory");
    __builtin_amdgcn_s_barrier();
    int cur = 0;
    for (int t = 0; t < NT; ++t) {
        if (t + 1 < NT) stage(cur ^ 1, (t + 1) << 5);
        half8 af[2], bf[4];
        #pragma unroll
        for (int i = 0; i < 2; ++i) af[i] = *(const half8*)&smA[cur * 2048 + aidx[i]];
        #pragma unroll
        for (int i = 0; i < 4; ++i) bf[i] = *(const half8*)&smB[cur * 4096 + bidx[i]];
        #pragma unroll
        for (int mi = 0; mi < 2; ++mi)
            #pragma unroll
            for (int ni = 0; ni < 4; ++ni)
                acc[mi][ni] = __builtin_amdgcn_mfma_f32_16x16x32_f16(af[mi], bf[ni], acc[mi][ni], 0, 0, 0);
        asm volatile("s_waitcnt vmcnt(0)" ::: "memory");
        __builtin_amdgcn_s_barrier();
        cur ^= 1;
    }
    const int col0 = (int)bn + wc * 64 + (lane & 15);
    const int row0 = (int)bm + wr * 32 + (lane >> 4) * 4;
    #pragma unroll
    for (int ni = 0; ni < 4; ++ni) {
        int col = col0 + ni * 16;
        float bz = bias[col];
        #pragma unroll
        for (int mi = 0; mi < 2; ++mi) {
            #pragma unroll
            for (int q = 0; q < 4; ++q) {
                int row = row0 + mi * 16 + q;
                float v = acc[mi][ni][q] + bz;
                if (RELU) v = fmaxf(v, 0.f);
                C[(size_t)row * N + col] = (f16)v;
            }
        }
    }
}

template<bool RELU, bool LIMIT>
__global__ __launch_bounds__(256)
void gemm_f16_kernel(const f16* __restrict__ A, const f16* __restrict__ BT,
                     f16* __restrict__ C, const float* __restrict__ bias,
                     const int* __restrict__ limit, int N, int K) {
    __shared__ __align__(16) f16 smA[2 * 2048];
    __shared__ __align__(16) f16 smB[2 * 4096];
    gemm_tile<RELU, LIMIT>(smA, smB, A, BT, C, bias, limit, blockIdx.x, blockIdx.y, N, K);
}

// merged s2 + abuf launch: blocks [0,xsplit) -> s2 (LIMIT), rest -> abuf
__global__ __launch_bounds__(256)
void gemm_dual_kernel(const f16* __restrict__ A0, const f16* __restrict__ BT0, f16* __restrict__ C0,
                      const float* __restrict__ bias0, const int* __restrict__ limit, int K0,
                      const f16* __restrict__ A1, const f16* __restrict__ BT1, f16* __restrict__ C1,
                      const float* __restrict__ bias1, int K1, int xsplit, int N) {
    __shared__ __align__(16) f16 smA[2 * 2048];
    __shared__ __align__(16) f16 smB[2 * 4096];
    if ((int)blockIdx.x < xsplit)
        gemm_tile<false, true>(smA, smB, A0, BT0, C0, bias0, limit, blockIdx.x, blockIdx.y, N, K0);
    else
        gemm_tile<false, false>(smA, smB, A1, BT1, C1, bias1, nullptr, blockIdx.x - xsplit, blockIdx.y, N, K1);
}

// ================= LayerNorm + relu over 1024 f16 cols (unique rows) =================
__global__ __launch_bounds__(256)
void ln_relu_f16_kernel(f16* __restrict__ s, const float* __restrict__ g,
                        const float* __restrict__ b, const int* __restrict__ nn) {
    int row = blockIdx.x;
    if (row >= *nn) return;
    f16* p = s + (size_t)row * FC1;
    int tid = threadIdx.x;
    half4 v = *(const half4*)&p[tid * 4];
    float f0 = (float)v[0], f1 = (float)v[1], f2 = (float)v[2], f3 = (float)v[3];
    float sum = f0 + f1 + f2 + f3;
    float sq = f0 * f0 + f1 * f1 + f2 * f2 + f3 * f3;
    #pragma unroll
    for (int off = 32; off > 0; off >>= 1) {
        sum += __shfl_down(sum, off);
        sq  += __shfl_down(sq, off);
    }
    __shared__ float ssum[4], ssq[4];
    int wid = tid >> 6;
    if ((tid & 63) == 0) { ssum[wid] = sum; ssq[wid] = sq; }
    __syncthreads();
    float tot = ssum[0] + ssum[1] + ssum[2] + ssum[3];
    float tq  = ssq[0] + ssq[1] + ssq[2] + ssq[3];
    float mu = tot * (1.0f / FC1);
    float var = tq * (1.0f / FC1) - mu * mu;
    float rs = rsqrtf(var + 1e-5f);
    float4 gg = *(const float4*)&g[tid * 4];
    float4 bb = *(const float4*)&b[tid * 4];
    half4 o;
    o[0] = (f16)fmaxf((f0 - mu) * rs * gg.x + bb.x, 0.f);
    o[1] = (f16)fmaxf((f1 - mu) * rs * gg.y + bb.y, 0.f);
    o[2] = (f16)fmaxf((f2 - mu) * rs * gg.z + bb.z, 0.f);
    o[3] = (f16)fmaxf((f3 - mu) * rs * gg.w + bb.w, 0.f);
    *(half4*)&p[tid * 4] = o;
}

// ================= final: relu(LN(s2[slot]) + a) @ Wq + bq =================
__global__ __launch_bounds__(256)
void final_f16_kernel(const f16* __restrict__ s2, const f16* __restrict__ ab,
                      const int* __restrict__ agent_slot,
                      const float* __restrict__ g2, const float* __restrict__ b2,
                      const float* __restrict__ Wq, const float* __restrict__ bq,
                      float* __restrict__ out) {
    int row = blockIdx.x;
    int slot = agent_slot[row];
    const f16* p = s2 + (size_t)slot * FC2;
    int tid = threadIdx.x;
    float v0 = (float)p[tid * 2], v1 = (float)p[tid * 2 + 1];
    float sum = v0 + v1;
    float sq = v0 * v0 + v1 * v1;
    #pragma unroll
    for (int off = 32; off > 0; off >>= 1) {
        sum += __shfl_down(sum, off);
        sq  += __shfl_down(sq, off);
    }
    __shared__ float ssum[4], ssq[4], spart[4];
    int wid = tid >> 6;
    if ((tid & 63) == 0) { ssum[wid] = sum; ssq[wid] = sq; }
    __syncthreads();
    float tot = ssum[0] + ssum[1] + ssum[2] + ssum[3];
    float tq  = ssq[0] + ssq[1] + ssq[2] + ssq[3];
    float mu = tot * (1.0f / FC2);
    float var = tq * (1.0f / FC2) - mu * mu;
    float rs = rsqrtf(var + 1e-5f);
    float a0 = (float)ab[(size_t)row * FC2 + tid * 2];
    float a1 = (float)ab[(size_t)row * FC2 + tid * 2 + 1];
    float g0 = g2[tid * 2], g1 = g2[tid * 2 + 1];
    float bb0 = b2[tid * 2], bb1 = b2[tid * 2 + 1];
    float sa0 = fmaxf((v0 - mu) * rs * g0 + bb0 + a0, 0.f);
    float sa1 = fmaxf((v1 - mu) * rs * g1 + bb1 + a1, 0.f);
    float part = sa0 * Wq[tid * 2] + sa1 * Wq[tid * 2 + 1];
    #pragma unroll
    for (int off = 32; off > 0; off >>= 1) part += __shfl_down(part, off);
    if ((tid & 63) == 0) spart[wid] = part;
    __syncthreads();
    if (tid == 0) out[row] = spart[0] + spart[1] + spart[2] + spart[3] + bq[0];
}

// ================= launch =================
extern "C" void kernel_launch(void* const* d_in, const int* in_sizes, int n_in,
                              void* d_out, int out_size, void* d_ws, size_t ws_size,
                              hipStream_t stream) {
    const float* x        = (const float*)d_in[0];
    const float* action   = (const float*)d_in[1];
    const int*   edge     = (const int*)d_in[2];
    const int*   agent_idx= (const int*)d_in[3];
    const float* W_gcn    = (const float*)d_in[4];
    const float* b_gcn    = (const float*)d_in[5];
    const float* W1       = (const float*)d_in[6];
    const float* b1       = (const float*)d_in[7];
    const float* g1       = (const float*)d_in[8];
    const float* beta1    = (const float*)d_in[9];
    const float* W2       = (const float*)d_in[10];
    const float* b2       = (const float*)d_in[11];
    const float* g2       = (const float*)d_in[12];
    const float* beta2    = (const float*)d_in[13];
    const float* Wa       = (const float*)d_in[14];
    const float* ba       = (const float*)d_in[15];
    const float* Wq       = (const float*)d_in[16];
    const float* bq       = (const float*)d_in[17];
    float* out = (float*)d_out;

    const int N = in_sizes[0] / IN_DIM;   // 50000
    const int E = in_sizes[2] / 2;        // 800000
    const int A = in_sizes[3];            // 16384
    const int* esrc = edge;
    const int* edst = edge + E;

    char* ws = (char*)d_ws;
    size_t off = 0;
    auto carve = [&](size_t bytes) -> char* {
        char* p = ws + off;
        off += (bytes + 255) & ~(size_t)255;
        return p;
    };
    int*   degcnt     = (int*)  carve((size_t)N * 4);
    int*   needed     = (int*)  carve((size_t)N * 4);
    float* dinv       = (float*)carve((size_t)N * 4);
    int*   offs       = (int*)  carve((size_t)N * 4);
    int*   cursor     = (int*)  carve((size_t)N * 4);
    int*   partials   = (int*)  carve(1024 * 4);
    int*   needed_list= (int*)  carve((size_t)A * 4);
    int*   n_needed   = (int*)  carve(256);
    int*   agent_slot = (int*)  carve((size_t)A * 4);
    int*   srcbuf     = (int*)  carve((size_t)E * 4);
    f16*   WgcnT      = (f16*)  carve((size_t)HID * IN_DIM * 2);
    f16*   W1T        = (f16*)  carve((size_t)FC1 * HID * 2);
    f16*   W2T        = (f16*)  carve((size_t)FC2 * FC1 * 2);
    f16*   WaT        = (f16*)  carve((size_t)FC2 * NACT * 2);
    f16*   act16      = (f16*)  carve((size_t)A * NACT * 2);
    f16*   x16        = (f16*)  carve((size_t)N * IN_DIM * 2);
    f16*   xagg       = (f16*)  carve((size_t)A * IN_DIM * 2);
    f16*   z          = (f16*)  carve((size_t)A * HID * 2);
    f16*   s1         = (f16*)  carve((size_t)A * FC1 * 2);
    f16*   s2         = (f16*)  carve((size_t)A * FC2 * 2);
    f16*   abuf       = (f16*)  carve((size_t)A * FC2 * 2);
    (void)ws_size;

    const int nblk_scan = (N + 255) / 256;       // 196
    const int eblk = (E + 255) / 256;            // 3125

    prep_kernel<<<196 + 32 + 256 + 512 + 32 + 512 + eblk, 256, 0, stream>>>(
        W_gcn, W1, W2, Wa, action, x, WgcnT, W1T, W2T, WaT, act16, x16,
        degcnt, needed, n_needed, N, A);
    markdeg_kernel<<<64 + eblk, 256, 0, stream>>>(agent_idx, edst, needed, needed_list,
                                                  n_needed, degcnt, A, E);
    dss_kernel<<<nblk_scan + 64, 256, 0, stream>>>(degcnt, needed, agent_idx, dinv,
                                                   offs, partials, agent_slot, N, A);
    addback_kernel<<<nblk_scan, 256, 0, stream>>>(offs, partials, cursor, N, nblk_scan);
    fill_kernel<<<eblk, 256, 0, stream>>>(esrc, edst, needed, cursor, srcbuf, E);
    gather_x_kernel<<<(A + 3) / 4, 256, 0, stream>>>(needed_list, n_needed, offs, degcnt,
                                                     srcbuf, dinv, x16, xagg);
    // z = relu(xagg @ Wgcn + b_gcn)   [U,256]
    gemm_f16_kernel<true, true><<<dim3(A / 64, HID / 128), 256, 0, stream>>>(
        xagg, WgcnT, z, b_gcn, n_needed, HID, IN_DIM);
    // s1 = z @ W1 + b1                [U,1024]
    gemm_f16_kernel<false, true><<<dim3(A / 64, FC1 / 128), 256, 0, stream>>>(
        z, W1T, s1, b1, n_needed, FC1, HID);
    // s1 = relu(LN(s1))
    ln_relu_f16_kernel<<<A, 256, 0, stream>>>(s1, g1, beta1, n_needed);
    // s2 = s1 @ W2 + b2 [U,512]  ||  abuf = action @ Wa + ba [A,512]
    gemm_dual_kernel<<<dim3(2 * (A / 64), FC2 / 128), 256, 0, stream>>>(
        s1, W2T, s2, b2, n_needed, FC1,
        act16, WaT, abuf, ba, NACT, A / 64, FC2);
    // out = relu(LN(s2[slot]) + abuf) @ Wq + bq
    final_f16_kernel<<<A, 256, 0, stream>>>(s2, abuf, agent_slot, g2, beta2, Wq, bq, out);
}

// Round 6
// 175.438 us; speedup vs baseline: 8.1335x; 1.0348x over previous
//
#include <hip/hip_runtime.h>
#include <hip/hip_bf16.h>

typedef _Float16 f16;
typedef _Float16 __attribute__((ext_vector_type(8))) half8;
typedef _Float16 __attribute__((ext_vector_type(4))) half4;
typedef float __attribute__((ext_vector_type(4))) floatx4;

#define IN_DIM 128
#define HID    256
#define FC1    1024
#define FC2    512
#define NACT   64

// ================= fused prep =================
__device__ __forceinline__ void transpose_tile(const float* __restrict__ in, f16* __restrict__ out,
                                               int K, int N, int bx, int by, int tid) {
    __shared__ f16 tile[32][33];
    int k0 = bx * 32, n0 = by * 32;
    int tx = tid & 31, ty = tid >> 5;
    #pragma unroll
    for (int i = 0; i < 4; ++i)
        tile[ty + i * 8][tx] = (f16)in[(size_t)(k0 + ty + i * 8) * N + n0 + tx];
    __syncthreads();
    #pragma unroll
    for (int i = 0; i < 4; ++i)
        out[(size_t)(n0 + ty + i * 8) * K + k0 + tx] = tile[tx][ty + i * 8];
}

__device__ __forceinline__ void cvt8(const float* __restrict__ in, f16* __restrict__ out, long gi) {
    float4 a = *(const float4*)&in[gi * 8];
    float4 b = *(const float4*)&in[gi * 8 + 4];
    half8 pk;
    pk[0] = (f16)a.x; pk[1] = (f16)a.y; pk[2] = (f16)a.z; pk[3] = (f16)a.w;
    pk[4] = (f16)b.x; pk[5] = (f16)b.y; pk[6] = (f16)b.z; pk[7] = (f16)b.w;
    *(half8*)&out[gi * 8] = pk;
}

__global__ __launch_bounds__(256)
void prep_kernel(const float* __restrict__ Wgcn, const float* __restrict__ W1,
                 const float* __restrict__ W2, const float* __restrict__ Wa,
                 const float* __restrict__ action, const float* __restrict__ x,
                 f16* WgcnT, f16* W1T, f16* W2T, f16* WaT, f16* act16, f16* x16,
                 int* degcnt, int* needed, int* n_needed, int N, int A) {
    int b = blockIdx.x, tid = threadIdx.x;
    if (b < 196) {
        int i = b * 256 + tid;
        if (i < N) { degcnt[i] = 0; needed[i] = 0; }
        if (b == 0 && tid == 0) *n_needed = 0;
        return;
    }
    b -= 196;
    if (b < 32)  { transpose_tile(Wgcn, WgcnT, IN_DIM, HID, b & 3, b >> 2, tid); return; }
    b -= 32;
    if (b < 256) { transpose_tile(W1, W1T, HID, FC1, b & 7, b >> 3, tid); return; }
    b -= 256;
    if (b < 512) { transpose_tile(W2, W2T, FC1, FC2, b & 31, b >> 5, tid); return; }
    b -= 512;
    if (b < 32)  { transpose_tile(Wa, WaT, NACT, FC2, b & 1, b >> 1, tid); return; }
    b -= 32;
    if (b < 512) { cvt8(action, act16, (long)b * 256 + tid); return; }
    b -= 512;
    cvt8(x, x16, (long)b * 256 + tid);   // 3125 blocks
}

// ================= CSR build =================
__global__ void markdeg_kernel(const int* __restrict__ agent_idx, const int* __restrict__ edst,
                               int* __restrict__ needed, int* __restrict__ needed_list,
                               int* __restrict__ n_needed, int* __restrict__ degcnt, int A, int E) {
    int b = blockIdx.x;
    if (b < 64) {
        int i = b * 256 + threadIdx.x;
        if (i < A) {
            int idx = agent_idx[i];
            if (atomicCAS(&needed[idx], 0, -1) == 0) {
                int p = atomicAdd(n_needed, 1);
                needed_list[p] = idx;
                needed[idx] = p + 1;
            }
        }
        return;
    }
    int e = (b - 64) * 256 + threadIdx.x;
    if (e < E) atomicAdd(&degcnt[edst[e]], 1);
}

// dinv + agent_slot + scan1, fused
__global__ void dss_kernel(const int* __restrict__ degcnt, const int* __restrict__ needed,
                           const int* __restrict__ agent_idx, float* __restrict__ dinv,
                           int* __restrict__ offs, int* __restrict__ partials,
                           int* __restrict__ agent_slot, int N, int A) {
    int b = blockIdx.x;
    if (b < 196) {
        __shared__ int sh[256];
        int tid = threadIdx.x;
        int i = b * 256 + tid;
        int dc = (i < N) ? degcnt[i] : 0;
        if (i < N) dinv[i] = rsqrtf((float)dc + 1.0f);  // +1 self-loop
        int v = (i < N && needed[i] != 0) ? dc : 0;
        sh[tid] = v;
        __syncthreads();
        #pragma unroll
        for (int d = 1; d < 256; d <<= 1) {
            int t = (tid >= d) ? sh[tid - d] : 0;
            __syncthreads();
            sh[tid] += t;
            __syncthreads();
        }
        if (i < N) offs[i] = sh[tid] - v;
        if (tid == 255) partials[b] = sh[255];
        return;
    }
    int i = (b - 196) * 256 + threadIdx.x;
    if (i < A) agent_slot[i] = needed[agent_idx[i]] - 1;
}

// addback with fused scan of partials
__global__ void addback_kernel(int* __restrict__ offs, const int* __restrict__ partials,
                               int* __restrict__ cursor, int n, int nblk) {
    __shared__ int sh[256];
    int tid = threadIdx.x;
    int v = (tid < nblk) ? partials[tid] : 0;
    sh[tid] = v;
    __syncthreads();
    #pragma unroll
    for (int d = 1; d < 256; d <<= 1) {
        int t = (tid >= d) ? sh[tid - d] : 0;
        __syncthreads();
        sh[tid] += t;
        __syncthreads();
    }
    int base = (blockIdx.x == 0) ? 0 : sh[blockIdx.x - 1];
    int i = blockIdx.x * 256 + tid;
    if (i < n) {
        int o = offs[i] + base;
        offs[i] = o;
        cursor[i] = o;
    }
}

__global__ void fill_kernel(const int* __restrict__ src, const int* __restrict__ dst,
                            const int* __restrict__ needed, int* __restrict__ cursor,
                            int* __restrict__ srcbuf, int E) {
    int e = blockIdx.x * blockDim.x + threadIdx.x;
    if (e < E) {
        int d = dst[e];
        if (needed[d] != 0) {
            int pos = atomicAdd(&cursor[d], 1);
            srcbuf[pos] = src[e];
        }
    }
}

// ================= aggregate x (f16 in, f32 acc, f16 out) =================
__global__ __launch_bounds__(256)
void gather_x_kernel(const int* __restrict__ needed_list, const int* __restrict__ n_needed,
                     const int* __restrict__ offs, const int* __restrict__ degcnt,
                     const int* __restrict__ srcbuf, const float* __restrict__ dinv,
                     const f16* __restrict__ x16, f16* __restrict__ xagg) {
    int w = (blockIdx.x * 256 + threadIdx.x) >> 6;
    int lane = threadIdx.x & 63;
    if (w >= *n_needed) return;
    int d = needed_list[w];
    float dd = dinv[d];
    int beg = offs[d], cnt = degcnt[d];
    union { unsigned u; f16 h[2]; } ld0, ld1;
    ld0.u = *(const unsigned*)&x16[(size_t)d * IN_DIM + lane * 2];
    float ax = (float)ld0.h[0] * dd * dd, ay = (float)ld0.h[1] * dd * dd;
    int j = 0;
    for (; j + 1 < cnt; j += 2) {
        int s0 = srcbuf[beg + j], s1 = srcbuf[beg + j + 1];
        float n0 = dinv[s0] * dd, n1 = dinv[s1] * dd;
        ld0.u = *(const unsigned*)&x16[(size_t)s0 * IN_DIM + lane * 2];
        ld1.u = *(const unsigned*)&x16[(size_t)s1 * IN_DIM + lane * 2];
        ax = fmaf((float)ld0.h[0], n0, ax);
        ay = fmaf((float)ld0.h[1], n0, ay);
        ax = fmaf((float)ld1.h[0], n1, ax);
        ay = fmaf((float)ld1.h[1], n1, ay);
    }
    if (j < cnt) {
        int s0 = srcbuf[beg + j];
        float n0 = dinv[s0] * dd;
        ld0.u = *(const unsigned*)&x16[(size_t)s0 * IN_DIM + lane * 2];
        ax = fmaf((float)ld0.h[0], n0, ax);
        ay = fmaf((float)ld0.h[1], n0, ay);
    }
    union { f16 h[2]; unsigned u; } pk;
    pk.h[0] = (f16)ax; pk.h[1] = (f16)ay;
    *(unsigned*)&xagg[(size_t)w * IN_DIM + lane * 2] = pk.u;
}

// ================= f16 MFMA GEMM tile body =================
// 64x128 tile, BK=64 (row = 128B = one full bank wrap; XOR swizzle slot^(r&7)
// gives 2-way-max bank aliasing on ds_read_b128 = free). 4 waves (2x2), each
// wave 32x64 = 2x4 frags of 16x16x32. Double-buffered, issue-early staging.
template<bool RELU, bool LIMIT>
__device__ __forceinline__ void gemm_tile(f16* __restrict__ smA, f16* __restrict__ smB,
                                          const f16* __restrict__ A, const f16* __restrict__ BT,
                                          f16* __restrict__ C, const float* __restrict__ bias,
                                          const int* __restrict__ limit,
                                          int bx, int by, int N, int K) {
    if (LIMIT && bx * 64 >= *limit) return;
    const int tid = threadIdx.x;
    const int lane = tid & 63;
    const int wave = tid >> 6;
    const int wr = wave >> 1, wc = wave & 1;
    const long bm = (long)bx * 64, bn = (long)by * 128;

    // staging: chunk ci -> row r=ci>>3, slot s=ci&7 holds global k-chunk s^(r&7)
    size_t aoff[2], boff[4];
    #pragma unroll
    for (int t = 0; t < 2; ++t) {
        int ci = t * 256 + tid;
        int r = ci >> 3, s = ci & 7, ks = s ^ (r & 7);
        aoff[t] = (size_t)(bm + r) * K + ks * 8;
    }
    #pragma unroll
    for (int t = 0; t < 4; ++t) {
        int ci = t * 256 + tid;
        int r = ci >> 3, s = ci & 7, ks = s ^ (r & 7);
        boff[t] = (size_t)(bn + r) * K + ks * 8;
    }
    // fragment LDS indices (f16 units): row*64 + swizzled-slot*8
    int aidx[2][2], bidx[2][4];
    const int kc = lane >> 4;
    #pragma unroll
    for (int kk = 0; kk < 2; ++kk) {
        #pragma unroll
        for (int i = 0; i < 2; ++i) {
            int ar = wr * 32 + i * 16 + (lane & 15);
            aidx[kk][i] = ar * 64 + ((kk * 4 + kc) ^ (ar & 7)) * 8;
        }
        #pragma unroll
        for (int i = 0; i < 4; ++i) {
            int br = wc * 64 + i * 16 + (lane & 15);
            bidx[kk][i] = br * 64 + ((kk * 4 + kc) ^ (br & 7)) * 8;
        }
    }

    const int NT = K >> 6;
    auto stage = [&](int buf, int k0) {
        #pragma unroll
        for (int t = 0; t < 2; ++t)
            __builtin_amdgcn_global_load_lds(
                (const __attribute__((address_space(1))) void*)(A + aoff[t] + k0),
                (__attribute__((address_space(3))) void*)(&smA[buf * 4096 + (t * 256 + tid) * 8]), 16, 0, 0);
        #pragma unroll
        for (int t = 0; t < 4; ++t)
            __builtin_amdgcn_global_load_lds(
                (const __attribute__((address_space(1))) void*)(BT + boff[t] + k0),
                (__attribute__((address_space(3))) void*)(&smB[buf * 8192 + (t * 256 + tid) * 8]), 16, 0, 0);
    };

    floatx4 acc[2][4] = {};
    stage(0, 0);
    asm volatile("s_waitcnt vmcnt(0)" ::: "memory");
    __builtin_amdgcn_s_barrier();
    int cur = 0;
    for (int t = 0; t < NT; ++t) {
        if (t + 1 < NT) stage(cur ^ 1, (t + 1) << 6);   // issue next-tile loads early
        #pragma unroll
        for (int kk = 0; kk < 2; ++kk) {
            half8 af[2], bf[4];
            #pragma unroll
            for (int i = 0; i < 2; ++i) af[i] = *(const half8*)&smA[cur * 4096 + aidx[kk][i]];
            #pragma unroll
            for (int i = 0; i < 4; ++i) bf[i] = *(const half8*)&smB[cur * 8192 + bidx[kk][i]];
            #pragma unroll
            for (int mi = 0; mi < 2; ++mi)
                #pragma unroll
                for (int ni = 0; ni < 4; ++ni)
                    acc[mi][ni] = __builtin_amdgcn_mfma_f32_16x16x32_f16(af[mi], bf[ni], acc[mi][ni], 0, 0, 0);
        }
        asm volatile("s_waitcnt vmcnt(0)" ::: "memory");
        __builtin_amdgcn_s_barrier();
        cur ^= 1;
    }
    const int col0 = (int)bn + wc * 64 + (lane & 15);
    const int row0 = (int)bm + wr * 32 + (lane >> 4) * 4;
    #pragma unroll
    for (int ni = 0; ni < 4; ++ni) {
        int col = col0 + ni * 16;
        float bz = bias[col];
        #pragma unroll
        for (int mi = 0; mi < 2; ++mi) {
            #pragma unroll
            for (int q = 0; q < 4; ++q) {
                int row = row0 + mi * 16 + q;
                float v = acc[mi][ni][q] + bz;
                if (RELU) v = fmaxf(v, 0.f);
                C[(size_t)row * N + col] = (f16)v;
            }
        }
    }
}

template<bool RELU, bool LIMIT>
__global__ __launch_bounds__(256)
void gemm_f16_kernel(const f16* __restrict__ A, const f16* __restrict__ BT,
                     f16* __restrict__ C, const float* __restrict__ bias,
                     const int* __restrict__ limit, int N, int K) {
    __shared__ __align__(16) f16 smA[2 * 4096];
    __shared__ __align__(16) f16 smB[2 * 8192];
    gemm_tile<RELU, LIMIT>(smA, smB, A, BT, C, bias, limit, blockIdx.x, blockIdx.y, N, K);
}

// merged s2 + abuf launch: blocks [0,xsplit) -> s2 (LIMIT), rest -> abuf
__global__ __launch_bounds__(256)
void gemm_dual_kernel(const f16* __restrict__ A0, const f16* __restrict__ BT0, f16* __restrict__ C0,
                      const float* __restrict__ bias0, const int* __restrict__ limit, int K0,
                      const f16* __restrict__ A1, const f16* __restrict__ BT1, f16* __restrict__ C1,
                      const float* __restrict__ bias1, int K1, int xsplit, int N) {
    __shared__ __align__(16) f16 smA[2 * 4096];
    __shared__ __align__(16) f16 smB[2 * 8192];
    if ((int)blockIdx.x < xsplit)
        gemm_tile<false, true>(smA, smB, A0, BT0, C0, bias0, limit, blockIdx.x, blockIdx.y, N, K0);
    else
        gemm_tile<false, false>(smA, smB, A1, BT1, C1, bias1, nullptr, blockIdx.x - xsplit, blockIdx.y, N, K1);
}

// ================= LayerNorm + relu over 1024 f16 cols (unique rows) =================
__global__ __launch_bounds__(256)
void ln_relu_f16_kernel(f16* __restrict__ s, const float* __restrict__ g,
                        const float* __restrict__ b, const int* __restrict__ nn) {
    int row = blockIdx.x;
    if (row >= *nn) return;
    f16* p = s + (size_t)row * FC1;
    int tid = threadIdx.x;
    half4 v = *(const half4*)&p[tid * 4];
    float f0 = (float)v[0], f1 = (float)v[1], f2 = (float)v[2], f3 = (float)v[3];
    float sum = f0 + f1 + f2 + f3;
    float sq = f0 * f0 + f1 * f1 + f2 * f2 + f3 * f3;
    #pragma unroll
    for (int off = 32; off > 0; off >>= 1) {
        sum += __shfl_down(sum, off);
        sq  += __shfl_down(sq, off);
    }
    __shared__ float ssum[4], ssq[4];
    int wid = tid >> 6;
    if ((tid & 63) == 0) { ssum[wid] = sum; ssq[wid] = sq; }
    __syncthreads();
    float tot = ssum[0] + ssum[1] + ssum[2] + ssum[3];
    float tq  = ssq[0] + ssq[1] + ssq[2] + ssq[3];
    float mu = tot * (1.0f / FC1);
    float var = tq * (1.0f / FC1) - mu * mu;
    float rs = rsqrtf(var + 1e-5f);
    float4 gg = *(const float4*)&g[tid * 4];
    float4 bb = *(const float4*)&b[tid * 4];
    half4 o;
    o[0] = (f16)fmaxf((f0 - mu) * rs * gg.x + bb.x, 0.f);
    o[1] = (f16)fmaxf((f1 - mu) * rs * gg.y + bb.y, 0.f);
    o[2] = (f16)fmaxf((f2 - mu) * rs * gg.z + bb.z, 0.f);
    o[3] = (f16)fmaxf((f3 - mu) * rs * gg.w + bb.w, 0.f);
    *(half4*)&p[tid * 4] = o;
}

// ================= final: relu(LN(s2[slot]) + a) @ Wq + bq =================
__global__ __launch_bounds__(256)
void final_f16_kernel(const f16* __restrict__ s2, const f16* __restrict__ ab,
                      const int* __restrict__ agent_slot,
                      const float* __restrict__ g2, const float* __restrict__ b2,
                      const float* __restrict__ Wq, const float* __restrict__ bq,
                      float* __restrict__ out) {
    int row = blockIdx.x;
    int slot = agent_slot[row];
    const f16* p = s2 + (size_t)slot * FC2;
    int tid = threadIdx.x;
    float v0 = (float)p[tid * 2], v1 = (float)p[tid * 2 + 1];
    float sum = v0 + v1;
    float sq = v0 * v0 + v1 * v1;
    #pragma unroll
    for (int off = 32; off > 0; off >>= 1) {
        sum += __shfl_down(sum, off);
        sq  += __shfl_down(sq, off);
    }
    __shared__ float ssum[4], ssq[4], spart[4];
    int wid = tid >> 6;
    if ((tid & 63) == 0) { ssum[wid] = sum; ssq[wid] = sq; }
    __syncthreads();
    float tot = ssum[0] + ssum[1] + ssum[2] + ssum[3];
    float tq  = ssq[0] + ssq[1] + ssq[2] + ssq[3];
    float mu = tot * (1.0f / FC2);
    float var = tq * (1.0f / FC2) - mu * mu;
    float rs = rsqrtf(var + 1e-5f);
    float a0 = (float)ab[(size_t)row * FC2 + tid * 2];
    float a1 = (float)ab[(size_t)row * FC2 + tid * 2 + 1];
    float g0 = g2[tid * 2], g1 = g2[tid * 2 + 1];
    float bb0 = b2[tid * 2], bb1 = b2[tid * 2 + 1];
    float sa0 = fmaxf((v0 - mu) * rs * g0 + bb0 + a0, 0.f);
    float sa1 = fmaxf((v1 - mu) * rs * g1 + bb1 + a1, 0.f);
    float part = sa0 * Wq[tid * 2] + sa1 * Wq[tid * 2 + 1];
    #pragma unroll
    for (int off = 32; off > 0; off >>= 1) part += __shfl_down(part, off);
    if ((tid & 63) == 0) spart[wid] = part;
    __syncthreads();
    if (tid == 0) out[row] = spart[0] + spart[1] + spart[2] + spart[3] + bq[0];
}

// ================= launch =================
extern "C" void kernel_launch(void* const* d_in, const int* in_sizes, int n_in,
                              void* d_out, int out_size, void* d_ws, size_t ws_size,
                              hipStream_t stream) {
    const float* x        = (const float*)d_in[0];
    const float* action   = (const float*)d_in[1];
    const int*   edge     = (const int*)d_in[2];
    const int*   agent_idx= (const int*)d_in[3];
    const float* W_gcn    = (const float*)d_in[4];
    const float* b_gcn    = (const float*)d_in[5];
    const float* W1       = (const float*)d_in[6];
    const float* b1       = (const float*)d_in[7];
    const float* g1       = (const float*)d_in[8];
    const float* beta1    = (const float*)d_in[9];
    const float* W2       = (const float*)d_in[10];
    const float* b2       = (const float*)d_in[11];
    const float* g2       = (const float*)d_in[12];
    const float* beta2    = (const float*)d_in[13];
    const float* Wa       = (const float*)d_in[14];
    const float* ba       = (const float*)d_in[15];
    const float* Wq       = (const float*)d_in[16];
    const float* bq       = (const float*)d_in[17];
    float* out = (float*)d_out;

    const int N = in_sizes[0] / IN_DIM;   // 50000
    const int E = in_sizes[2] / 2;        // 800000
    const int A = in_sizes[3];            // 16384
    const int* esrc = edge;
    const int* edst = edge + E;

    char* ws = (char*)d_ws;
    size_t off = 0;
    auto carve = [&](size_t bytes) -> char* {
        char* p = ws + off;
        off += (bytes + 255) & ~(size_t)255;
        return p;
    };
    int*   degcnt     = (int*)  carve((size_t)N * 4);
    int*   needed     = (int*)  carve((size_t)N * 4);
    float* dinv       = (float*)carve((size_t)N * 4);
    int*   offs       = (int*)  carve((size_t)N * 4);
    int*   cursor     = (int*)  carve((size_t)N * 4);
    int*   partials   = (int*)  carve(1024 * 4);
    int*   needed_list= (int*)  carve((size_t)A * 4);
    int*   n_needed   = (int*)  carve(256);
    int*   agent_slot = (int*)  carve((size_t)A * 4);
    int*   srcbuf     = (int*)  carve((size_t)E * 4);
    f16*   WgcnT      = (f16*)  carve((size_t)HID * IN_DIM * 2);
    f16*   W1T        = (f16*)  carve((size_t)FC1 * HID * 2);
    f16*   W2T        = (f16*)  carve((size_t)FC2 * FC1 * 2);
    f16*   WaT        = (f16*)  carve((size_t)FC2 * NACT * 2);
    f16*   act16      = (f16*)  carve((size_t)A * NACT * 2);
    f16*   x16        = (f16*)  carve((size_t)N * IN_DIM * 2);
    f16*   xagg       = (f16*)  carve((size_t)A * IN_DIM * 2);
    f16*   z          = (f16*)  carve((size_t)A * HID * 2);
    f16*   s1         = (f16*)  carve((size_t)A * FC1 * 2);
    f16*   s2         = (f16*)  carve((size_t)A * FC2 * 2);
    f16*   abuf       = (f16*)  carve((size_t)A * FC2 * 2);
    (void)ws_size;

    const int nblk_scan = (N + 255) / 256;       // 196
    const int eblk = (E + 255) / 256;            // 3125

    prep_kernel<<<196 + 32 + 256 + 512 + 32 + 512 + eblk, 256, 0, stream>>>(
        W_gcn, W1, W2, Wa, action, x, WgcnT, W1T, W2T, WaT, act16, x16,
        degcnt, needed, n_needed, N, A);
    markdeg_kernel<<<64 + eblk, 256, 0, stream>>>(agent_idx, edst, needed, needed_list,
                                                  n_needed, degcnt, A, E);
    dss_kernel<<<nblk_scan + 64, 256, 0, stream>>>(degcnt, needed, agent_idx, dinv,
                                                   offs, partials, agent_slot, N, A);
    addback_kernel<<<nblk_scan, 256, 0, stream>>>(offs, partials, cursor, N, nblk_scan);
    fill_kernel<<<eblk, 256, 0, stream>>>(esrc, edst, needed, cursor, srcbuf, E);
    gather_x_kernel<<<(A + 3) / 4, 256, 0, stream>>>(needed_list, n_needed, offs, degcnt,
                                                     srcbuf, dinv, x16, xagg);
    // z = relu(xagg @ Wgcn + b_gcn)   [U,256]
    gemm_f16_kernel<true, true><<<dim3(A / 64, HID / 128), 256, 0, stream>>>(
        xagg, WgcnT, z, b_gcn, n_needed, HID, IN_DIM);
    // s1 = z @ W1 + b1                [U,1024]
    gemm_f16_kernel<false, true><<<dim3(A / 64, FC1 / 128), 256, 0, stream>>>(
        z, W1T, s1, b1, n_needed, FC1, HID);
    // s1 = relu(LN(s1))
    ln_relu_f16_kernel<<<A, 256, 0, stream>>>(s1, g1, beta1, n_needed);
    // s2 = s1 @ W2 + b2 [U,512]  ||  abuf = action @ Wa + ba [A,512]
    gemm_dual_kernel<<<dim3(2 * (A / 64), FC2 / 128), 256, 0, stream>>>(
        s1, W2T, s2, b2, n_needed, FC1,
        act16, WaT, abuf, ba, NACT, A / 64, FC2);
    // out = relu(LN(s2[slot]) + abuf) @ Wq + bq
    final_f16_kernel<<<A, 256, 0, stream>>>(s2, abuf, agent_slot, g2, beta2, Wq, bq, out);
}

// Round 7
// 172.987 us; speedup vs baseline: 8.2488x; 1.0142x over previous
//
#include <hip/hip_runtime.h>
#include <hip/hip_bf16.h>

typedef _Float16 f16;
typedef _Float16 __attribute__((ext_vector_type(8))) half8;
typedef _Float16 __attribute__((ext_vector_type(4))) half4;
typedef float __attribute__((ext_vector_type(4))) floatx4;

#define IN_DIM 128
#define HID    256
#define FC1    1024
#define FC2    512
#define NACT   64

// ================= fused prep =================
__device__ __forceinline__ void transpose_tile(const float* __restrict__ in, f16* __restrict__ out,
                                               int K, int N, int bx, int by, int tid) {
    __shared__ f16 tile[32][33];
    int k0 = bx * 32, n0 = by * 32;
    int tx = tid & 31, ty = tid >> 5;
    #pragma unroll
    for (int i = 0; i < 4; ++i)
        tile[ty + i * 8][tx] = (f16)in[(size_t)(k0 + ty + i * 8) * N + n0 + tx];
    __syncthreads();
    #pragma unroll
    for (int i = 0; i < 4; ++i)
        out[(size_t)(n0 + ty + i * 8) * K + k0 + tx] = tile[tx][ty + i * 8];
}

__device__ __forceinline__ void cvt8(const float* __restrict__ in, f16* __restrict__ out, long gi) {
    float4 a = *(const float4*)&in[gi * 8];
    float4 b = *(const float4*)&in[gi * 8 + 4];
    half8 pk;
    pk[0] = (f16)a.x; pk[1] = (f16)a.y; pk[2] = (f16)a.z; pk[3] = (f16)a.w;
    pk[4] = (f16)b.x; pk[5] = (f16)b.y; pk[6] = (f16)b.z; pk[7] = (f16)b.w;
    *(half8*)&out[gi * 8] = pk;
}

__global__ __launch_bounds__(256)
void prep_kernel(const float* __restrict__ Wgcn, const float* __restrict__ W1,
                 const float* __restrict__ W2, const float* __restrict__ Wa,
                 const float* __restrict__ action, const float* __restrict__ x,
                 f16* WgcnT, f16* W1T, f16* W2T, f16* WaT, f16* act16, f16* x16,
                 int* degcnt, int* needed, int* n_needed, int N, int A) {
    int b = blockIdx.x, tid = threadIdx.x;
    if (b < 196) {
        int i = b * 256 + tid;
        if (i < N) { degcnt[i] = 0; needed[i] = 0; }
        if (b == 0 && tid == 0) *n_needed = 0;
        return;
    }
    b -= 196;
    if (b < 32)  { transpose_tile(Wgcn, WgcnT, IN_DIM, HID, b & 3, b >> 2, tid); return; }
    b -= 32;
    if (b < 256) { transpose_tile(W1, W1T, HID, FC1, b & 7, b >> 3, tid); return; }
    b -= 256;
    if (b < 512) { transpose_tile(W2, W2T, FC1, FC2, b & 31, b >> 5, tid); return; }
    b -= 512;
    if (b < 32)  { transpose_tile(Wa, WaT, NACT, FC2, b & 1, b >> 1, tid); return; }
    b -= 32;
    if (b < 512) { cvt8(action, act16, (long)b * 256 + tid); return; }
    b -= 512;
    cvt8(x, x16, (long)b * 256 + tid);   // 3125 blocks
}

// ================= CSR build =================
__global__ void markdeg_kernel(const int* __restrict__ agent_idx, const int* __restrict__ edst,
                               int* __restrict__ needed, int* __restrict__ needed_list,
                               int* __restrict__ n_needed, int* __restrict__ degcnt, int A, int E) {
    int b = blockIdx.x;
    if (b < 64) {
        int i = b * 256 + threadIdx.x;
        if (i < A) {
            int idx = agent_idx[i];
            if (atomicCAS(&needed[idx], 0, -1) == 0) {
                int p = atomicAdd(n_needed, 1);
                needed_list[p] = idx;
                needed[idx] = p + 1;
            }
        }
        return;
    }
    int e = (b - 64) * 256 + threadIdx.x;
    if (e < E) atomicAdd(&degcnt[edst[e]], 1);
}

// dinv + agent_slot + scan1, fused
__global__ void dss_kernel(const int* __restrict__ degcnt, const int* __restrict__ needed,
                           const int* __restrict__ agent_idx, float* __restrict__ dinv,
                           int* __restrict__ offs, int* __restrict__ partials,
                           int* __restrict__ agent_slot, int N, int A) {
    int b = blockIdx.x;
    if (b < 196) {
        __shared__ int sh[256];
        int tid = threadIdx.x;
        int i = b * 256 + tid;
        int dc = (i < N) ? degcnt[i] : 0;
        if (i < N) dinv[i] = rsqrtf((float)dc + 1.0f);  // +1 self-loop
        int v = (i < N && needed[i] != 0) ? dc : 0;
        sh[tid] = v;
        __syncthreads();
        #pragma unroll
        for (int d = 1; d < 256; d <<= 1) {
            int t = (tid >= d) ? sh[tid - d] : 0;
            __syncthreads();
            sh[tid] += t;
            __syncthreads();
        }
        if (i < N) offs[i] = sh[tid] - v;
        if (tid == 255) partials[b] = sh[255];
        return;
    }
    int i = (b - 196) * 256 + threadIdx.x;
    if (i < A) agent_slot[i] = needed[agent_idx[i]] - 1;
}

// addback with fused scan of partials
__global__ void addback_kernel(int* __restrict__ offs, const int* __restrict__ partials,
                               int* __restrict__ cursor, int n, int nblk) {
    __shared__ int sh[256];
    int tid = threadIdx.x;
    int v = (tid < nblk) ? partials[tid] : 0;
    sh[tid] = v;
    __syncthreads();
    #pragma unroll
    for (int d = 1; d < 256; d <<= 1) {
        int t = (tid >= d) ? sh[tid - d] : 0;
        __syncthreads();
        sh[tid] += t;
        __syncthreads();
    }
    int base = (blockIdx.x == 0) ? 0 : sh[blockIdx.x - 1];
    int i = blockIdx.x * 256 + tid;
    if (i < n) {
        int o = offs[i] + base;
        offs[i] = o;
        cursor[i] = o;
    }
}

__global__ void fill_kernel(const int* __restrict__ src, const int* __restrict__ dst,
                            const int* __restrict__ needed, int* __restrict__ cursor,
                            int* __restrict__ srcbuf, int E) {
    int e = blockIdx.x * blockDim.x + threadIdx.x;
    if (e < E) {
        int d = dst[e];
        if (needed[d] != 0) {
            int pos = atomicAdd(&cursor[d], 1);
            srcbuf[pos] = src[e];
        }
    }
}

// ================= aggregate x (f16 in, f32 acc, f16 out) =================
__global__ __launch_bounds__(256)
void gather_x_kernel(const int* __restrict__ needed_list, const int* __restrict__ n_needed,
                     const int* __restrict__ offs, const int* __restrict__ degcnt,
                     const int* __restrict__ srcbuf, const float* __restrict__ dinv,
                     const f16* __restrict__ x16, f16* __restrict__ xagg) {
    int w = (blockIdx.x * 256 + threadIdx.x) >> 6;
    int lane = threadIdx.x & 63;
    if (w >= *n_needed) return;
    int d = needed_list[w];
    float dd = dinv[d];
    int beg = offs[d], cnt = degcnt[d];
    union { unsigned u; f16 h[2]; } ld0, ld1, ld2, ld3;
    ld0.u = *(const unsigned*)&x16[(size_t)d * IN_DIM + lane * 2];
    float ax = (float)ld0.h[0] * dd * dd, ay = (float)ld0.h[1] * dd * dd;
    int j = 0;
    for (; j + 3 < cnt; j += 4) {   // 4-deep for memory-level parallelism
        int s0 = srcbuf[beg + j], s1 = srcbuf[beg + j + 1];
        int s2 = srcbuf[beg + j + 2], s3 = srcbuf[beg + j + 3];
        float n0 = dinv[s0] * dd, n1 = dinv[s1] * dd;
        float n2 = dinv[s2] * dd, n3 = dinv[s3] * dd;
        ld0.u = *(const unsigned*)&x16[(size_t)s0 * IN_DIM + lane * 2];
        ld1.u = *(const unsigned*)&x16[(size_t)s1 * IN_DIM + lane * 2];
        ld2.u = *(const unsigned*)&x16[(size_t)s2 * IN_DIM + lane * 2];
        ld3.u = *(const unsigned*)&x16[(size_t)s3 * IN_DIM + lane * 2];
        ax = fmaf((float)ld0.h[0], n0, ax); ay = fmaf((float)ld0.h[1], n0, ay);
        ax = fmaf((float)ld1.h[0], n1, ax); ay = fmaf((float)ld1.h[1], n1, ay);
        ax = fmaf((float)ld2.h[0], n2, ax); ay = fmaf((float)ld2.h[1], n2, ay);
        ax = fmaf((float)ld3.h[0], n3, ax); ay = fmaf((float)ld3.h[1], n3, ay);
    }
    for (; j < cnt; ++j) {
        int s0 = srcbuf[beg + j];
        float n0 = dinv[s0] * dd;
        ld0.u = *(const unsigned*)&x16[(size_t)s0 * IN_DIM + lane * 2];
        ax = fmaf((float)ld0.h[0], n0, ax);
        ay = fmaf((float)ld0.h[1], n0, ay);
    }
    union { f16 h[2]; unsigned u; } pk;
    pk.h[0] = (f16)ax; pk.h[1] = (f16)ay;
    *(unsigned*)&xagg[(size_t)w * IN_DIM + lane * 2] = pk.u;
}

// ================= f16 MFMA GEMM tile body =================
// 64x64 tile, BK=64 (row = 128B = one bank wrap; XOR swizzle slot^(r&7) -> 2-way max).
// 4 waves (2x2), each wave 32x32 = 2x2 frags. 32KB LDS -> 5 blocks/CU (20 waves/CU):
// TLP hides the vmcnt(0) staging drain that bounded the 64x128 version.
template<bool RELU, bool LIMIT>
__device__ __forceinline__ void gemm_tile(f16* __restrict__ smA, f16* __restrict__ smB,
                                          const f16* __restrict__ A, const f16* __restrict__ BT,
                                          f16* __restrict__ C, const float* __restrict__ bias,
                                          const int* __restrict__ limit,
                                          int bx, int by, int N, int K) {
    if (LIMIT && bx * 64 >= *limit) return;
    const int tid = threadIdx.x;
    const int lane = tid & 63;
    const int wave = tid >> 6;
    const int wr = wave >> 1, wc = wave & 1;
    const long bm = (long)bx * 64, bn = (long)by * 64;

    // staging: chunk ci -> row r=ci>>3, slot s=ci&7 holds global k-chunk s^(r&7)
    size_t aoff[2], boff[2];
    #pragma unroll
    for (int t = 0; t < 2; ++t) {
        int ci = t * 256 + tid;
        int r = ci >> 3, s = ci & 7, ks = s ^ (r & 7);
        aoff[t] = (size_t)(bm + r) * K + ks * 8;
        boff[t] = (size_t)(bn + r) * K + ks * 8;
    }
    // fragment LDS indices (f16 units): row*64 + swizzled-slot*8
    int aidx[2][2], bidx[2][2];
    const int kc = lane >> 4;
    #pragma unroll
    for (int kk = 0; kk < 2; ++kk) {
        #pragma unroll
        for (int i = 0; i < 2; ++i) {
            int ar = wr * 32 + i * 16 + (lane & 15);
            aidx[kk][i] = ar * 64 + ((kk * 4 + kc) ^ (ar & 7)) * 8;
            int br = wc * 32 + i * 16 + (lane & 15);
            bidx[kk][i] = br * 64 + ((kk * 4 + kc) ^ (br & 7)) * 8;
        }
    }

    const int NT = K >> 6;
    auto stage = [&](int buf, int k0) {
        #pragma unroll
        for (int t = 0; t < 2; ++t) {
            __builtin_amdgcn_global_load_lds(
                (const __attribute__((address_space(1))) void*)(A + aoff[t] + k0),
                (__attribute__((address_space(3))) void*)(&smA[buf * 4096 + (t * 256 + tid) * 8]), 16, 0, 0);
            __builtin_amdgcn_global_load_lds(
                (const __attribute__((address_space(1))) void*)(BT + boff[t] + k0),
                (__attribute__((address_space(3))) void*)(&smB[buf * 4096 + (t * 256 + tid) * 8]), 16, 0, 0);
        }
    };

    floatx4 acc[2][2] = {};
    stage(0, 0);
    asm volatile("s_waitcnt vmcnt(0)" ::: "memory");
    __builtin_amdgcn_s_barrier();
    int cur = 0;
    for (int t = 0; t < NT; ++t) {
        if (t + 1 < NT) stage(cur ^ 1, (t + 1) << 6);   // issue next-tile loads early
        #pragma unroll
        for (int kk = 0; kk < 2; ++kk) {
            half8 af[2], bf[2];
            #pragma unroll
            for (int i = 0; i < 2; ++i) {
                af[i] = *(const half8*)&smA[cur * 4096 + aidx[kk][i]];
                bf[i] = *(const half8*)&smB[cur * 4096 + bidx[kk][i]];
            }
            #pragma unroll
            for (int mi = 0; mi < 2; ++mi)
                #pragma unroll
                for (int ni = 0; ni < 2; ++ni)
                    acc[mi][ni] = __builtin_amdgcn_mfma_f32_16x16x32_f16(af[mi], bf[ni], acc[mi][ni], 0, 0, 0);
        }
        asm volatile("s_waitcnt vmcnt(0)" ::: "memory");
        __builtin_amdgcn_s_barrier();
        cur ^= 1;
    }
    const int col0 = (int)bn + wc * 32 + (lane & 15);
    const int row0 = (int)bm + wr * 32 + (lane >> 4) * 4;
    #pragma unroll
    for (int ni = 0; ni < 2; ++ni) {
        int col = col0 + ni * 16;
        float bz = bias[col];
        #pragma unroll
        for (int mi = 0; mi < 2; ++mi) {
            #pragma unroll
            for (int q = 0; q < 4; ++q) {
                int row = row0 + mi * 16 + q;
                float v = acc[mi][ni][q] + bz;
                if (RELU) v = fmaxf(v, 0.f);
                C[(size_t)row * N + col] = (f16)v;
            }
        }
    }
}

template<bool RELU, bool LIMIT>
__global__ __launch_bounds__(256)
void gemm_f16_kernel(const f16* __restrict__ A, const f16* __restrict__ BT,
                     f16* __restrict__ C, const float* __restrict__ bias,
                     const int* __restrict__ limit, int N, int K) {
    __shared__ __align__(16) f16 smA[2 * 4096];
    __shared__ __align__(16) f16 smB[2 * 4096];
    gemm_tile<RELU, LIMIT>(smA, smB, A, BT, C, bias, limit, blockIdx.x, blockIdx.y, N, K);
}

// merged s2 + abuf launch: blocks [0,xsplit) -> s2 (LIMIT), rest -> abuf
__global__ __launch_bounds__(256)
void gemm_dual_kernel(const f16* __restrict__ A0, const f16* __restrict__ BT0, f16* __restrict__ C0,
                      const float* __restrict__ bias0, const int* __restrict__ limit, int K0,
                      const f16* __restrict__ A1, const f16* __restrict__ BT1, f16* __restrict__ C1,
                      const float* __restrict__ bias1, int K1, int xsplit, int N) {
    __shared__ __align__(16) f16 smA[2 * 4096];
    __shared__ __align__(16) f16 smB[2 * 4096];
    if ((int)blockIdx.x < xsplit)
        gemm_tile<false, true>(smA, smB, A0, BT0, C0, bias0, limit, blockIdx.x, blockIdx.y, N, K0);
    else
        gemm_tile<false, false>(smA, smB, A1, BT1, C1, bias1, nullptr, blockIdx.x - xsplit, blockIdx.y, N, K1);
}

// ================= LayerNorm + relu over 1024 f16 cols (unique rows) =================
__global__ __launch_bounds__(256)
void ln_relu_f16_kernel(f16* __restrict__ s, const float* __restrict__ g,
                        const float* __restrict__ b, const int* __restrict__ nn) {
    int row = blockIdx.x;
    if (row >= *nn) return;
    f16* p = s + (size_t)row * FC1;
    int tid = threadIdx.x;
    half4 v = *(const half4*)&p[tid * 4];
    float f0 = (float)v[0], f1 = (float)v[1], f2 = (float)v[2], f3 = (float)v[3];
    float sum = f0 + f1 + f2 + f3;
    float sq = f0 * f0 + f1 * f1 + f2 * f2 + f3 * f3;
    #pragma unroll
    for (int off = 32; off > 0; off >>= 1) {
        sum += __shfl_down(sum, off);
        sq  += __shfl_down(sq, off);
    }
    __shared__ float ssum[4], ssq[4];
    int wid = tid >> 6;
    if ((tid & 63) == 0) { ssum[wid] = sum; ssq[wid] = sq; }
    __syncthreads();
    float tot = ssum[0] + ssum[1] + ssum[2] + ssum[3];
    float tq  = ssq[0] + ssq[1] + ssq[2] + ssq[3];
    float mu = tot * (1.0f / FC1);
    float var = tq * (1.0f / FC1) - mu * mu;
    float rs = rsqrtf(var + 1e-5f);
    float4 gg = *(const float4*)&g[tid * 4];
    float4 bb = *(const float4*)&b[tid * 4];
    half4 o;
    o[0] = (f16)fmaxf((f0 - mu) * rs * gg.x + bb.x, 0.f);
    o[1] = (f16)fmaxf((f1 - mu) * rs * gg.y + bb.y, 0.f);
    o[2] = (f16)fmaxf((f2 - mu) * rs * gg.z + bb.z, 0.f);
    o[3] = (f16)fmaxf((f3 - mu) * rs * gg.w + bb.w, 0.f);
    *(half4*)&p[tid * 4] = o;
}

// ================= final: relu(LN(s2[slot]) + a) @ Wq + bq =================
__global__ __launch_bounds__(256)
void final_f16_kernel(const f16* __restrict__ s2, const f16* __restrict__ ab,
                      const int* __restrict__ agent_slot,
                      const float* __restrict__ g2, const float* __restrict__ b2,
                      const float* __restrict__ Wq, const float* __restrict__ bq,
                      float* __restrict__ out) {
    int row = blockIdx.x;
    int slot = agent_slot[row];
    const f16* p = s2 + (size_t)slot * FC2;
    int tid = threadIdx.x;
    float v0 = (float)p[tid * 2], v1 = (float)p[tid * 2 + 1];
    float sum = v0 + v1;
    float sq = v0 * v0 + v1 * v1;
    #pragma unroll
    for (int off = 32; off > 0; off >>= 1) {
        sum += __shfl_down(sum, off);
        sq  += __shfl_down(sq, off);
    }
    __shared__ float ssum[4], ssq[4], spart[4];
    int wid = tid >> 6;
    if ((tid & 63) == 0) { ssum[wid] = sum; ssq[wid] = sq; }
    __syncthreads();
    float tot = ssum[0] + ssum[1] + ssum[2] + ssum[3];
    float tq  = ssq[0] + ssq[1] + ssq[2] + ssq[3];
    float mu = tot * (1.0f / FC2);
    float var = tq * (1.0f / FC2) - mu * mu;
    float rs = rsqrtf(var + 1e-5f);
    float a0 = (float)ab[(size_t)row * FC2 + tid * 2];
    float a1 = (float)ab[(size_t)row * FC2 + tid * 2 + 1];
    float g0 = g2[tid * 2], g1 = g2[tid * 2 + 1];
    float bb0 = b2[tid * 2], bb1 = b2[tid * 2 + 1];
    float sa0 = fmaxf((v0 - mu) * rs * g0 + bb0 + a0, 0.f);
    float sa1 = fmaxf((v1 - mu) * rs * g1 + bb1 + a1, 0.f);
    float part = sa0 * Wq[tid * 2] + sa1 * Wq[tid * 2 + 1];
    #pragma unroll
    for (int off = 32; off > 0; off >>= 1) part += __shfl_down(part, off);
    if ((tid & 63) == 0) spart[wid] = part;
    __syncthreads();
    if (tid == 0) out[row] = spart[0] + spart[1] + spart[2] + spart[3] + bq[0];
}

// ================= launch =================
extern "C" void kernel_launch(void* const* d_in, const int* in_sizes, int n_in,
                              void* d_out, int out_size, void* d_ws, size_t ws_size,
                              hipStream_t stream) {
    const float* x        = (const float*)d_in[0];
    const float* action   = (const float*)d_in[1];
    const int*   edge     = (const int*)d_in[2];
    const int*   agent_idx= (const int*)d_in[3];
    const float* W_gcn    = (const float*)d_in[4];
    const float* b_gcn    = (const float*)d_in[5];
    const float* W1       = (const float*)d_in[6];
    const float* b1       = (const float*)d_in[7];
    const float* g1       = (const float*)d_in[8];
    const float* beta1    = (const float*)d_in[9];
    const float* W2       = (const float*)d_in[10];
    const float* b2       = (const float*)d_in[11];
    const float* g2       = (const float*)d_in[12];
    const float* beta2    = (const float*)d_in[13];
    const float* Wa       = (const float*)d_in[14];
    const float* ba       = (const float*)d_in[15];
    const float* Wq       = (const float*)d_in[16];
    const float* bq       = (const float*)d_in[17];
    float* out = (float*)d_out;

    const int N = in_sizes[0] / IN_DIM;   // 50000
    const int E = in_sizes[2] / 2;        // 800000
    const int A = in_sizes[3];            // 16384
    const int* esrc = edge;
    const int* edst = edge + E;

    char* ws = (char*)d_ws;
    size_t off = 0;
    auto carve = [&](size_t bytes) -> char* {
        char* p = ws + off;
        off += (bytes + 255) & ~(size_t)255;
        return p;
    };
    int*   degcnt     = (int*)  carve((size_t)N * 4);
    int*   needed     = (int*)  carve((size_t)N * 4);
    float* dinv       = (float*)carve((size_t)N * 4);
    int*   offs       = (int*)  carve((size_t)N * 4);
    int*   cursor     = (int*)  carve((size_t)N * 4);
    int*   partials   = (int*)  carve(1024 * 4);
    int*   needed_list= (int*)  carve((size_t)A * 4);
    int*   n_needed   = (int*)  carve(256);
    int*   agent_slot = (int*)  carve((size_t)A * 4);
    int*   srcbuf     = (int*)  carve((size_t)E * 4);
    f16*   WgcnT      = (f16*)  carve((size_t)HID * IN_DIM * 2);
    f16*   W1T        = (f16*)  carve((size_t)FC1 * HID * 2);
    f16*   W2T        = (f16*)  carve((size_t)FC2 * FC1 * 2);
    f16*   WaT        = (f16*)  carve((size_t)FC2 * NACT * 2);
    f16*   act16      = (f16*)  carve((size_t)A * NACT * 2);
    f16*   x16        = (f16*)  carve((size_t)N * IN_DIM * 2);
    f16*   xagg       = (f16*)  carve((size_t)A * IN_DIM * 2);
    f16*   z          = (f16*)  carve((size_t)A * HID * 2);
    f16*   s1         = (f16*)  carve((size_t)A * FC1 * 2);
    f16*   s2         = (f16*)  carve((size_t)A * FC2 * 2);
    f16*   abuf       = (f16*)  carve((size_t)A * FC2 * 2);
    (void)ws_size;

    const int nblk_scan = (N + 255) / 256;       // 196
    const int eblk = (E + 255) / 256;            // 3125

    prep_kernel<<<196 + 32 + 256 + 512 + 32 + 512 + eblk, 256, 0, stream>>>(
        W_gcn, W1, W2, Wa, action, x, WgcnT, W1T, W2T, WaT, act16, x16,
        degcnt, needed, n_needed, N, A);
    markdeg_kernel<<<64 + eblk, 256, 0, stream>>>(agent_idx, edst, needed, needed_list,
                                                  n_needed, degcnt, A, E);
    dss_kernel<<<nblk_scan + 64, 256, 0, stream>>>(degcnt, needed, agent_idx, dinv,
                                                   offs, partials, agent_slot, N, A);
    addback_kernel<<<nblk_scan, 256, 0, stream>>>(offs, partials, cursor, N, nblk_scan);
    fill_kernel<<<eblk, 256, 0, stream>>>(esrc, edst, needed, cursor, srcbuf, E);
    gather_x_kernel<<<(A + 3) / 4, 256, 0, stream>>>(needed_list, n_needed, offs, degcnt,
                                                     srcbuf, dinv, x16, xagg);
    // z = relu(xagg @ Wgcn + b_gcn)   [U,256]
    gemm_f16_kernel<true, true><<<dim3(A / 64, HID / 64), 256, 0, stream>>>(
        xagg, WgcnT, z, b_gcn, n_needed, HID, IN_DIM);
    // s1 = z @ W1 + b1                [U,1024]
    gemm_f16_kernel<false, true><<<dim3(A / 64, FC1 / 64), 256, 0, stream>>>(
        z, W1T, s1, b1, n_needed, FC1, HID);
    // s1 = relu(LN(s1))
    ln_relu_f16_kernel<<<A, 256, 0, stream>>>(s1, g1, beta1, n_needed);
    // s2 = s1 @ W2 + b2 [U,512]  ||  abuf = action @ Wa + ba [A,512]
    gemm_dual_kernel<<<dim3(2 * (A / 64), FC2 / 64), 256, 0, stream>>>(
        s1, W2T, s2, b2, n_needed, FC1,
        act16, WaT, abuf, ba, NACT, A / 64, FC2);
    // out = relu(LN(s2[slot]) + abuf) @ Wq + bq
    final_f16_kernel<<<A, 256, 0, stream>>>(s2, abuf, agent_slot, g2, beta2, Wq, bq, out);
}